// Round 11
// baseline (457.677 us; speedup 1.0000x reference)
//
#include <hip/hip_runtime.h>

#define BB 8
#define IC 32
#define OC 64
#define HH 256
#define WW 256
#define EPS 1e-5f

// padded xt geometry (halo 3 top/left, 5 bottom/right; interior rows/cols 3..258)
#define XTW 264
#define XTP (XTW * XTW)      // 69696 px per batch
// padded Y geometry (conv1 output, halo 2 each side; interior 2..257)
#define YW 260
#define YP (YW * YW)         // 67600 px per batch

typedef __attribute__((ext_vector_type(8))) short bf16x8;
typedef __attribute__((ext_vector_type(4))) float f32x4;

#define YSTR 40   // fused/edge ys per-pixel stride in shorts
#define XSTR 40   // fallback xs per-pixel stride in shorts

// ---- workspace layout (float indices) ----
#define WS_GAP   0
#define WS_BIDX  256
#define WS_W1F   264                    // conv1 A-frags (bf16)
#define WS_B1F   (WS_W1F + 9216)
#define WS_W2F   (WS_B1F + 64)          // conv2 A-frags (bf16)
#define WS_B2F   (WS_W2F + 51200)
#define WS_SXWT  (WS_B2F + 64)          // edge bf16 MFMA A-frags
#define WS_SXBF  (WS_SXWT + 51200)
#define WS_SYWT  (WS_SXBF + 64)
#define WS_SYBF  (WS_SYWT + 51200)
#define WS_LWT   (WS_SYBF + 64)
#define WS_LBF   (WS_LWT + 51200)
// ---- fast-path extension ----
#define WS_XT    (WS_LBF + 64)          // 8 * 69696 px * 32ch bf16 (padded NHWC x)
#define WS_ZPAD  (WS_XT + 8921088)      // 16 floats of zeros
#define WS_NEED_FAST ((size_t)(WS_ZPAD + 16) * 4)
// ---- split-path extension (Y intermediate; verified engaged in R11) ----
#define WS_Y     (WS_ZPAD + 16)         // 8 * 67600 px * 64ch bf16 = 17305600 floats
#define WS_NEED_SPLIT ((size_t)(WS_Y + 17305600) * 4)

__device__ inline unsigned short bf16r(float f) {
    unsigned int u = __float_as_uint(f);
    unsigned int r = (u + 0x7fffu + ((u >> 16) & 1u)) >> 16;
    return (unsigned short)r;
}
__device__ inline float bf2f(unsigned short s) {
    return __uint_as_float(((unsigned int)s) << 16);
}

__device__ __forceinline__ void gld16(const void* g, const void* l) {
    __builtin_amdgcn_global_load_lds(
        (const __attribute__((address_space(1))) void*)(unsigned long long)(g),
        (__attribute__((address_space(3))) void*)(unsigned int)(unsigned long long)(l),
        16, 0, 0);
}

// ------------------------------------------------------------------
// prep: fold BN scales into weights; when split, zero Y's halo ring.
// ------------------------------------------------------------------
__global__ void prep_kernel(const float* __restrict__ mw1, const float* __restrict__ mb1, const float* __restrict__ mbn1,
                            const float* __restrict__ mw2, const float* __restrict__ mb2, const float* __restrict__ mbn2,
                            const float* __restrict__ sxw, const float* __restrict__ sxb, const float* __restrict__ sxbn,
                            const float* __restrict__ syw, const float* __restrict__ syb, const float* __restrict__ sybn,
                            const float* __restrict__ lw,  const float* __restrict__ lb,  const float* __restrict__ lbn,
                            float* __restrict__ ws, int fast, int split) {
    int idx = blockIdx.x * 256 + threadIdx.x;

    if (idx < 18432) {  // conv1 A-frags
        int j = idx & 7, lane = (idx >> 3) & 63, oct = (idx >> 9) & 1, ht = idx >> 10;
        int t = ht % 9, h = ht / 9;
        int oc = h * 32 + oct * 16 + (lane & 15);
        int ic = (lane >> 4) * 8 + j;
        float s = mbn1[oc] * rsqrtf(mbn1[192 + oc] + EPS);
        ((unsigned short*)(ws + WS_W1F))[idx] = bf16r(mw1[(oc * IC + ic) * 9 + t] * s);
    }
    if (idx < 102400) {  // conv2 A-frags
        int j = idx & 7, lane = (idx >> 3) & 63, oct = (idx >> 9) & 3, ht = idx >> 11;
        int t = ht % 25, h = ht / 25;
        int oc = oct * 16 + (lane & 15);
        int ic = h * 32 + (lane >> 4) * 8 + j;
        float s = mbn2[oc] * rsqrtf(mbn2[192 + oc] + EPS);
        ((unsigned short*)(ws + WS_W2F))[idx] = bf16r(mw2[(oc * OC + ic) * 25 + t] * s);
    }
    if (idx < 51200) {  // edge 5x5 bf16 A-frags
        int j = idx & 7, lane = (idx >> 3) & 63, oct = (idx >> 9) & 3, t = idx >> 11;
        int oc = oct * 16 + (lane & 15);
        int ic = (lane >> 4) * 8 + j;
        float ssx = sxbn[oc] * rsqrtf(sxbn[192 + oc] + EPS);
        float ssy = sybn[oc] * rsqrtf(sybn[192 + oc] + EPS);
        float sl  = lbn[oc]  * rsqrtf(lbn[192 + oc]  + EPS);
        ((unsigned short*)(ws + WS_SXWT))[idx] = bf16r(sxw[(oc * IC + ic) * 25 + t] * ssx);
        ((unsigned short*)(ws + WS_SYWT))[idx] = bf16r(syw[(oc * IC + ic) * 25 + t] * ssy);
        ((unsigned short*)(ws + WS_LWT ))[idx] = bf16r(lw [(oc * IC + ic) * 25 + t] * sl);
    }
    if (idx < 256) ws[WS_GAP + idx] = 0.f;
    if (fast && idx < 16) ws[WS_ZPAD + idx] = 0.f;
    if (split) {
        // zero Y halo: 2064 halo px/batch x 8 batches x 8 chunks = 132096
        #pragma unroll
        for (int rep = 0; rep < 2; rep++) {
            int id = idx + rep * 102400;
            if (id < 132096) {
                int bb = id / 16512, rm = id % 16512;
                int hp = rm >> 3, ch = rm & 7;
                int row, col;
                if (hp < 1040) { int rr = hp / 260; row = (rr < 2) ? rr : 256 + rr; col = hp % 260; }
                else { int j2 = hp - 1040; row = 2 + (j2 >> 2); int cv = j2 & 3; col = (cv < 2) ? cv : 256 + cv; }
                *(uint4*)((short*)(ws + WS_Y) + (((size_t)bb * YP + row * YW + col) * 64 + ch * 8)) = make_uint4(0u, 0u, 0u, 0u);
            }
        }
    }
    if (idx < 64) {
        float s1 = mbn1[idx] * rsqrtf(mbn1[192 + idx] + EPS);
        ws[WS_B1F + idx] = (mb1[idx] - mbn1[128 + idx]) * s1 + mbn1[64 + idx];
        float s2 = mbn2[idx] * rsqrtf(mbn2[192 + idx] + EPS);
        ws[WS_B2F + idx] = (mb2[idx] - mbn2[128 + idx]) * s2 + mbn2[64 + idx];
        float sx = sxbn[idx] * rsqrtf(sxbn[192 + idx] + EPS);
        ws[WS_SXBF + idx] = (sxb[idx] - sxbn[128 + idx]) * sx + sxbn[64 + idx];
        float sy = sybn[idx] * rsqrtf(sybn[192 + idx] + EPS);
        ws[WS_SYBF + idx] = (syb[idx] - sybn[128 + idx]) * sy + sybn[64 + idx];
        float sl = lbn[idx] * rsqrtf(lbn[192 + idx] + EPS);
        ws[WS_LBF + idx] = (lb[idx] - lbn[128 + idx]) * sl + lbn[64 + idx];
    }
}

// ------------------------------------------------------------------
// FAST path: NCHW fp32 -> padded NHWC bf16 xt (+ halo zeroing) + GAP.
// ------------------------------------------------------------------
__global__ void __launch_bounds__(256, 2)
xform_kernel(const float* __restrict__ x, float* __restrict__ ws) {
    int b = blockIdx.y, row = blockIdx.x, t = threadIdx.x;
    const float* xb = x + (size_t)b * (IC * HH * WW) + (size_t)row * WW;
    short* xtB = (short*)(ws + WS_XT) + (size_t)b * XTP * 32;

    unsigned int pk[16];
    #pragma unroll
    for (int k = 0; k < 32; k += 2) {
        float v0 = xb[(size_t)k * (HH * WW) + t];
        float v1 = xb[(size_t)(k + 1) * (HH * WW) + t];
        pk[k >> 1] = (unsigned int)bf16r(v0) | ((unsigned int)bf16r(v1) << 16);
    }
    uint4* dp = (uint4*)(xtB + ((size_t)(row + 3) * XTW + (t + 3)) * 32);
    dp[0] = make_uint4(pk[0],  pk[1],  pk[2],  pk[3]);
    dp[1] = make_uint4(pk[4],  pk[5],  pk[6],  pk[7]);
    dp[2] = make_uint4(pk[8],  pk[9],  pk[10], pk[11]);
    dp[3] = make_uint4(pk[12], pk[13], pk[14], pk[15]);

    if (t < 32) {
        int px = t >> 2, q = t & 3;
        int col = (px < 3) ? px : 256 + px;
        ((uint4*)(xtB + ((size_t)(row + 3) * XTW + col) * 32))[q] = make_uint4(0u, 0u, 0u, 0u);
    }
    if (row == 0) {
        for (int i = t; i < 3 * XTW * 4; i += 256) {
            int px = i >> 2, q = i & 3;
            ((uint4*)(xtB + ((size_t)(px / XTW) * XTW + (px % XTW)) * 32))[q] = make_uint4(0u, 0u, 0u, 0u);
        }
    }
    if (row == HH - 1) {
        for (int i = t; i < 5 * XTW * 4; i += 256) {
            int px = i >> 2, q = i & 3;
            ((uint4*)(xtB + ((size_t)(259 + px / XTW) * XTW + (px % XTW)) * 32))[q] = make_uint4(0u, 0u, 0u, 0u);
        }
    }

    __shared__ float gl[32];
    int w = t >> 6, lane = t & 63;
    #pragma unroll
    for (int kk = 0; kk < 8; kk++) {
        int k = w * 8 + kk;
        const float* rp = xb + (size_t)k * (HH * WW);
        float s = rp[lane] + rp[lane + 64] + rp[lane + 128] + rp[lane + 192];
        #pragma unroll
        for (int off = 32; off; off >>= 1) s += __shfl_down(s, off, 64);
        if (lane == 0) gl[k] = s;
    }
    __syncthreads();
    if (t < 32) atomicAdd(ws + WS_GAP + b * 32 + t, gl[t] * (1.f / (HH * WW)));
}

__global__ void gap_kernel(const float* __restrict__ x, float* __restrict__ ws) {
    int bc = blockIdx.x;
    const float4* p = (const float4*)(x + (size_t)bc * (HH * WW));
    float s = 0.f;
    for (int i = threadIdx.x; i < (HH * WW) / 4; i += 256) {
        float4 v = p[i];
        s += (v.x + v.y) + (v.z + v.w);
    }
    #pragma unroll
    for (int off = 32; off; off >>= 1) s += __shfl_down(s, off, 64);
    __shared__ float red[4];
    int lane = threadIdx.x & 63, w = threadIdx.x >> 6;
    if (lane == 0) red[w] = s;
    __syncthreads();
    if (threadIdx.x == 0)
        ws[WS_GAP + bc] = (red[0] + red[1] + red[2] + red[3]) * (1.f / (HH * WW));
}

__global__ void gate_kernel(const float* __restrict__ w1, const float* __restrict__ b1,
                            const float* __restrict__ gbn,
                            const float* __restrict__ w2, const float* __restrict__ b2,
                            float* __restrict__ ws) {
    __shared__ float hsh[8][32];
    int tid = threadIdx.x;
    int b = tid >> 5, j = tid & 31;
    float acc = b1[j];
    for (int i = 0; i < 32; i++) acc += ws[WS_GAP + b * 32 + i] * w1[j * 32 + i];
    float s = gbn[j] * rsqrtf(gbn[96 + j] + EPS);
    hsh[b][j] = tanhf((acc - gbn[64 + j]) * s + gbn[32 + j]);
    __syncthreads();
    if (tid < 8) {
        float best = -1e30f; int bi = 0;
        for (int c = 0; c < 3; c++) {
            float k = b2[c];
            for (int jj = 0; jj < 32; jj++) k += hsh[tid][jj] * w2[c * 32 + jj];
            if (k > best) { best = k; bi = c; }
        }
        ((int*)ws)[WS_BIDX + tid] = bi;
    }
}

// ------------------------------------------------------------------
// SPLIT pass 1: conv1 3x3+bn+relu -> padded Y (bf16 NHWC). (R11-verified.)
// ------------------------------------------------------------------
__global__ void __launch_bounds__(256, 2)
conv1_kernel(float* __restrict__ ws) {
    __shared__ __align__(1024) short xs[10752];   // 21504 B (324 px * 64B + pad)

    int b = blockIdx.y;
    if (((const int*)ws)[WS_BIDX + b] != 0) return;
    int tile = blockIdx.x;
    int ty = (tile >> 4) * 16, tx = (tile & 15) * 16;
    int tid = threadIdx.x;
    int w = tid >> 6, lane = tid & 63, n = lane & 15, quad = lane >> 4;

    const short* xtb = (const short*)(ws + WS_XT) + (size_t)b * (XTP * 32);
    for (int c = w; c < 21; c += 4) {
        int D = c * 1024 + (lane << 4);
        int L = D ^ (((D >> 7) & 7) << 4);
        int pL = L >> 6, qL = (L >> 4) & 3;
        int rr = pL / 18, cc2 = pL - rr * 18;
        if (pL >= 324) { rr = 0; cc2 = 0; }   // tail chunks: harmless refetch
        const void* src = (const void*)(xtb + ((size_t)((ty + 2 + rr) * XTW + tx + 2 + cc2)) * 32 + (qL << 3));
        gld16(src, (const void*)((const char*)xs + c * 1024));
    }

    auto ldb = [&](int r, int c) -> bf16x8 {
        int L = ((r * 18 + c) << 6) + (quad << 4);
        int A = L ^ (((L >> 7) & 7) << 4);
        return *(const bf16x8*)((const char*)xs + A);
    };

    const short* w1v = (const short*)(ws + WS_W1F);
    short* Yb = (short*)(ws + WS_Y) + (size_t)b * ((size_t)YP * 64);

    f32x4 a1[4][4];
    #pragma unroll
    for (int i = 0; i < 4; i++)
        #pragma unroll
        for (int jj = 0; jj < 4; jj++) a1[i][jj] = (f32x4){0.f, 0.f, 0.f, 0.f};

    int R0 = w * 4;

    __syncthreads();  // xs staged (drains vmcnt)

    #pragma unroll
    for (int dw = 0; dw < 3; dw++) {
        bf16x8 w1f[3][4];
        #pragma unroll
        for (int dh = 0; dh < 3; dh++) {
            int t = dh * 3 + dw;
            #pragma unroll
            for (int o4 = 0; o4 < 4; o4++)
                w1f[dh][o4] = *(const bf16x8*)(w1v + (((((o4 >> 1) * 9 + t) * 2) + (o4 & 1)) * 64 + lane) * 8);
        }
        bf16x8 bfr[6];
        #pragma unroll
        for (int rI = 0; rI < 6; rI++)
            bfr[rI] = ldb(R0 + rI, n + dw);
        #pragma unroll
        for (int dh = 0; dh < 3; dh++)
            #pragma unroll
            for (int r4 = 0; r4 < 4; r4++) {
                #pragma unroll
                for (int o4 = 0; o4 < 4; o4++)
                    a1[r4][o4] = __builtin_amdgcn_mfma_f32_16x16x32_bf16(w1f[dh][o4], bfr[r4 + dh], a1[r4][o4], 0, 0, 0);
            }
    }

    #pragma unroll
    for (int o4 = 0; o4 < 4; o4++) {
        float bias1[4];
        #pragma unroll
        for (int r = 0; r < 4; r++)
            bias1[r] = ws[WS_B1F + o4 * 16 + quad * 4 + r];
        #pragma unroll
        for (int r4 = 0; r4 < 4; r4++) {
            float v0 = fmaxf(a1[r4][o4][0] + bias1[0], 0.f);
            float v1 = fmaxf(a1[r4][o4][1] + bias1[1], 0.f);
            float v2 = fmaxf(a1[r4][o4][2] + bias1[2], 0.f);
            float v3 = fmaxf(a1[r4][o4][3] + bias1[3], 0.f);
            uint2 pkk;
            pkk.x = (unsigned int)bf16r(v0) | ((unsigned int)bf16r(v1) << 16);
            pkk.y = (unsigned int)bf16r(v2) | ((unsigned int)bf16r(v3) << 16);
            int row = ty + R0 + r4 + 2, col = tx + n + 2;
            *(uint2*)(Yb + ((size_t)(row * YW + col)) * 64 + o4 * 16 + quad * 4) = pkk;
        }
    }
}

// ------------------------------------------------------------------
// SPLIT pass 2: conv2 5x5+bn+relu from padded Y.
// R13: 512-thread blocks, wave = (rowgroup rg=w>>1, oc-half oh=w&1):
// each wave computes 4 rows x 16 cols x 32 oc. Per-wave state acc[4][2]
// = 32 AGPR + ring afq[2][2]=16 + bfr2[8]=32 -> unified ~120 ->
// 4 waves/SIMD (16 waves/CU, 2 blocks x 51.2KB LDS). No barriers in the
// k-loop -> occupancy converts to MFMA duty (unlike R10's lockstep);
// per-block weight traffic unchanged (8 waves x half = 4 x full).
// Launch bound (512,2) = the R10-measured-safe 128-reg cap.
// ------------------------------------------------------------------
__global__ void __launch_bounds__(512, 2)
conv2_kernel(const float* __restrict__ ws, float* __restrict__ out) {
    __shared__ __align__(1024) short ysl[25600];   // 51200 B (400 px * 128B)

    int b = blockIdx.y;
    if (((const int*)ws)[WS_BIDX + b] != 0) return;
    int tile = blockIdx.x;
    int ty = (tile >> 4) * 16, tx = (tile & 15) * 16;
    int tid = threadIdx.x;
    int w = tid >> 6, lane = tid & 63, n = lane & 15, quad = lane >> 4;
    int rg = w >> 1, oh = w & 1;

    const short* Yb = (const short*)(ws + WS_Y) + (size_t)b * ((size_t)YP * 64);
    for (int c = w; c < 50; c += 8) {
        int D = c * 1024 + (lane << 4);
        int L = D ^ (((D >> 7) & 7) << 4);
        int pL = L >> 7, sub = (L >> 4) & 7;
        int rr = pL / 20, cc2 = pL - rr * 20;
        const void* src = (const void*)(Yb + ((size_t)((ty + rr) * YW + tx + cc2)) * 64 + (sub << 3));
        gld16(src, (const void*)((const char*)ysl + c * 1024));
    }

    auto ldy = [&](int px, int h) -> bf16x8 {
        int L = (px << 7) + (h << 6) + (quad << 4);
        int A = L ^ (((L >> 7) & 7) << 4);
        return *(const bf16x8*)((const char*)ysl + A);
    };

    const bf16x8* w2v = (const bf16x8*)(ws + WS_W2F);

    f32x4 acc2[4][2];
    #pragma unroll
    for (int i = 0; i < 4; i++)
        #pragma unroll
        for (int jj = 0; jj < 2; jj++) acc2[i][jj] = (f32x4){0.f, 0.f, 0.f, 0.f};
    int mrow0 = rg * 4;

    __syncthreads();  // ysl staged (drains vmcnt) — the ONLY barrier

    #pragma unroll 1
    for (int h = 0; h < 2; h++) {
        const bf16x8* w2h = w2v + (size_t)h * 100 * 64;
        bf16x8 afq[2][2];   // 2-deep k prefetch ring, this wave's 2 oc-tiles
        #pragma unroll
        for (int kp = 0; kp < 2; kp++) {
            int tn = (kp % 5) * 5 + (kp / 5);
            int base = tn * 256 + oh * 128 + lane;
            afq[kp][0] = w2h[base];  afq[kp][1] = w2h[base + 64];
        }
        bf16x8 bfr2[8];
        #pragma unroll
        for (int k = 0; k < 25; k++) {
            int dw = k / 5, dh = k % 5;
            if (dh == 0) {
                #pragma unroll
                for (int rI = 0; rI < 8; rI++)
                    bfr2[rI] = ldy((mrow0 + rI) * 20 + n + dw, h);
            }
            #pragma unroll
            for (int r4 = 0; r4 < 4; r4++) {
                bf16x8 bb = bfr2[r4 + dh];
                acc2[r4][0] = __builtin_amdgcn_mfma_f32_16x16x32_bf16(afq[k & 1][0], bb, acc2[r4][0], 0, 0, 0);
                acc2[r4][1] = __builtin_amdgcn_mfma_f32_16x16x32_bf16(afq[k & 1][1], bb, acc2[r4][1], 0, 0, 0);
            }
            if (k + 2 < 25) {
                int kk = k + 2;
                int tn = (kk % 5) * 5 + (kk / 5);
                int base = tn * 256 + oh * 128 + lane;
                afq[k & 1][0] = w2h[base];  afq[k & 1][1] = w2h[base + 64];
            }
        }
    }

    float bias2[2][4];
    #pragma unroll
    for (int j = 0; j < 2; j++)
        #pragma unroll
        for (int r = 0; r < 4; r++)
            bias2[j][r] = ws[WS_B2F + (oh * 2 + j) * 16 + quad * 4 + r];

    float* ob = out + (size_t)b * OC * HH * WW;
    #pragma unroll
    for (int r4 = 0; r4 < 4; r4++) {
        int orow = mrow0 + r4;
        #pragma unroll
        for (int j = 0; j < 2; j++) {
            #pragma unroll
            for (int r = 0; r < 4; r++) {
                int oc = (oh * 2 + j) * 16 + quad * 4 + r;
                float v = fmaxf(acc2[r4][j][r] + bias2[j][r], 0.f);
                ob[(size_t)oc * (HH * WW) + (ty + orow) * WW + tx + n] = v;
            }
        }
    }
}

// ------------------------------------------------------------------
// FUSED main (tier-2/3 fallback; R6-verified body).
// ------------------------------------------------------------------
template <int ASYNC>
__global__ void __launch_bounds__(256, 2)
main_kernel(const float* __restrict__ x, const float* __restrict__ ws, float* __restrict__ out) {
    __shared__ __align__(1024) short xs[ASYNC ? 496 * 32 : 484 * XSTR];
    __shared__ __align__(16)   short ys[400 * YSTR];

    int b = blockIdx.y;
    if (((const int*)ws)[WS_BIDX + b] != 0) return;
    int tile = blockIdx.x;
    int ty = (tile >> 4) * 16, tx = (tile & 15) * 16;
    int tid = threadIdx.x;
    int w = tid >> 6, lane = tid & 63, n = lane & 15, quad = lane >> 4;

    if constexpr (ASYNC) {
        const short* xtb = (const short*)(ws + WS_XT) + (size_t)b * (XTP * 32);
        for (int c = w; c < 31; c += 4) {
            int D = c * 1024 + (lane << 4);
            int L = D ^ (((D >> 7) & 7) << 4);
            int pL = L >> 6, qL = (L >> 4) & 3;
            int rr = pL / 22, cc2 = pL - rr * 22;
            if (pL >= 484) { rr = 21; cc2 = 21; }
            const void* src = (const void*)(xtb + ((size_t)((ty + rr) * XTW + tx + cc2)) * 32 + (qL << 3));
            gld16(src, (const void*)((const char*)xs + c * 1024));
        }
    } else {
        const float* xb = x + (size_t)b * IC * HH * WW;
        for (int p = tid; p < 484; p += 256) {
            int rr = p / 22, cc = p % 22;
            int gy = ty - 3 + rr, gx = tx - 3 + cc;
            bool v = ((unsigned)gy < HH) && ((unsigned)gx < WW);
            const float* xp = xb + gy * WW + gx;
            short* dst = xs + p * XSTR;
            #pragma unroll
            for (int ic = 0; ic < IC; ic += 4) {
                float f0 = v ? xp[(size_t)(ic + 0) * (HH * WW)] : 0.f;
                float f1 = v ? xp[(size_t)(ic + 1) * (HH * WW)] : 0.f;
                float f2 = v ? xp[(size_t)(ic + 2) * (HH * WW)] : 0.f;
                float f3 = v ? xp[(size_t)(ic + 3) * (HH * WW)] : 0.f;
                uint2 pk;
                pk.x = (unsigned int)bf16r(f0) | ((unsigned int)bf16r(f1) << 16);
                pk.y = (unsigned int)bf16r(f2) | ((unsigned int)bf16r(f3) << 16);
                *(uint2*)(dst + ic) = pk;
            }
        }
    }

    auto ldb = [&](int P) -> bf16x8 {
        if constexpr (ASYNC) {
            int L = (P << 6) + (quad << 4);
            int A = L ^ (((L >> 7) & 7) << 4);
            return *(const bf16x8*)((const char*)xs + A);
        } else {
            return *(const bf16x8*)(xs + P * XSTR + quad * 8);
        }
    };

    const short* w1v = (const short*)(ws + WS_W1F);
    const bf16x8* w2v = (const bf16x8*)(ws + WS_W2F);

    f32x4 acc2[4][4];
    #pragma unroll
    for (int i = 0; i < 4; i++)
        #pragma unroll
        for (int jj = 0; jj < 4; jj++) acc2[i][jj] = (f32x4){0.f, 0.f, 0.f, 0.f};
    int mrow0 = w * 4;
    int yr0   = w * 5;

    __syncthreads();

    #pragma unroll 1
    for (int h = 0; h < 2; h++) {
        if (h) __syncthreads();

        #pragma unroll
        for (int cg = 0; cg < 2; cg++) {
            int cb = cg * 4;
            f32x4 a1[5][2];
            #pragma unroll
            for (int rr = 0; rr < 5; rr++) {
                a1[rr][0] = (f32x4){0.f, 0.f, 0.f, 0.f};
                a1[rr][1] = (f32x4){0.f, 0.f, 0.f, 0.f};
            }
            #pragma unroll
            for (int dw = 0; dw < 3; dw++) {
                bf16x8 w1f[3][2];
                #pragma unroll
                for (int dh = 0; dh < 3; dh++) {
                    int t = dh * 3 + dw;
                    w1f[dh][0] = *(const bf16x8*)(w1v + (((h * 9 + t) * 2 + 0) * 64 + lane) * 8);
                    w1f[dh][1] = *(const bf16x8*)(w1v + (((h * 9 + t) * 2 + 1) * 64 + lane) * 8);
                }
                bf16x8 bfr[7];
                #pragma unroll
                for (int rI = 0; rI < 7; rI++)
                    bfr[rI] = ldb((yr0 + rI) * 22 + cb + n + dw);
                #pragma unroll
                for (int dh = 0; dh < 3; dh++)
                    #pragma unroll
                    for (int rr = 0; rr < 5; rr++) {
                        a1[rr][0] = __builtin_amdgcn_mfma_f32_16x16x32_bf16(w1f[dh][0], bfr[rr + dh], a1[rr][0], 0, 0, 0);
                        a1[rr][1] = __builtin_amdgcn_mfma_f32_16x16x32_bf16(w1f[dh][1], bfr[rr + dh], a1[rr][1], 0, 0, 0);
                    }
            }
            #pragma unroll
            for (int oct = 0; oct < 2; oct++) {
                float bias1[4];
                #pragma unroll
                for (int r = 0; r < 4; r++)
                    bias1[r] = ws[WS_B1F + h * 32 + oct * 16 + quad * 4 + r];
                #pragma unroll
                for (int rr = 0; rr < 5; rr++) {
                    int yr = yr0 + rr;
                    int gy2 = ty - 2 + yr, gx2 = tx - 2 + cb + n;
                    bool inb = ((unsigned)gy2 < HH) && ((unsigned)gx2 < WW);
                    float v0 = inb ? fmaxf(a1[rr][oct][0] + bias1[0], 0.f) : 0.f;
                    float v1 = inb ? fmaxf(a1[rr][oct][1] + bias1[1], 0.f) : 0.f;
                    float v2 = inb ? fmaxf(a1[rr][oct][2] + bias1[2], 0.f) : 0.f;
                    float v3 = inb ? fmaxf(a1[rr][oct][3] + bias1[3], 0.f) : 0.f;
                    uint2 pkk;
                    pkk.x = (unsigned int)bf16r(v0) | ((unsigned int)bf16r(v1) << 16);
                    pkk.y = (unsigned int)bf16r(v2) | ((unsigned int)bf16r(v3) << 16);
                    *(uint2*)(ys + (yr * 20 + cb + n) * YSTR + oct * 16 + quad * 4) = pkk;
                }
            }
        }
        __syncthreads();

        const bf16x8* w2h = w2v + (size_t)h * 100 * 64;
        bf16x8 afq[4][4];
        #pragma unroll
        for (int kp = 0; kp < 4; kp++) {
            int tn = (kp % 5) * 5 + (kp / 5);
            int base = tn * 256 + lane;
            afq[kp][0] = w2h[base];       afq[kp][1] = w2h[base + 64];
            afq[kp][2] = w2h[base + 128]; afq[kp][3] = w2h[base + 192];
        }
        bf16x8 bfr2[8];
        #pragma unroll
        for (int k = 0; k < 25; k++) {
            int dw = k / 5, dh = k % 5;
            if (dh == 0) {
                #pragma unroll
                for (int rI = 0; rI < 8; rI++)
                    bfr2[rI] = *(const bf16x8*)(ys + ((mrow0 + rI) * 20 + n + dw) * YSTR + quad * 8);
            }
            #pragma unroll
            for (int r4 = 0; r4 < 4; r4++) {
                bf16x8 bb = bfr2[r4 + dh];
                acc2[r4][0] = __builtin_amdgcn_mfma_f32_16x16x32_bf16(afq[k & 3][0], bb, acc2[r4][0], 0, 0, 0);
                acc2[r4][1] = __builtin_amdgcn_mfma_f32_16x16x32_bf16(afq[k & 3][1], bb, acc2[r4][1], 0, 0, 0);
                acc2[r4][2] = __builtin_amdgcn_mfma_f32_16x16x32_bf16(afq[k & 3][2], bb, acc2[r4][2], 0, 0, 0);
                acc2[r4][3] = __builtin_amdgcn_mfma_f32_16x16x32_bf16(afq[k & 3][3], bb, acc2[r4][3], 0, 0, 0);
            }
            if (k + 4 < 25) {
                int kk = k + 4;
                int tn = (kk % 5) * 5 + (kk / 5);
                int base = tn * 256 + lane;
                afq[k & 3][0] = w2h[base];       afq[k & 3][1] = w2h[base + 64];
                afq[k & 3][2] = w2h[base + 128]; afq[k & 3][3] = w2h[base + 192];
            }
        }
    }

    float bias2[4][4];
    #pragma unroll
    for (int oct = 0; oct < 4; oct++)
        #pragma unroll
        for (int r = 0; r < 4; r++)
            bias2[oct][r] = ws[WS_B2F + oct * 16 + quad * 4 + r];

    float* ob = out + (size_t)b * OC * HH * WW;
    #pragma unroll
    for (int r4 = 0; r4 < 4; r4++) {
        int orow = mrow0 + r4;
        #pragma unroll
        for (int oct = 0; oct < 4; oct++) {
            #pragma unroll
            for (int r = 0; r < 4; r++) {
                int oc = oct * 16 + quad * 4 + r;
                float v = fmaxf(acc2[r4][oct][r] + bias2[oct][r], 0.f);
                ob[(size_t)oc * (HH * WW) + (ty + orow) * WW + tx + n] = v;
            }
        }
    }
}

// ------------------------------------------------------------------
// edge branches via MFMA (R8-verified padded-xt staging; early-exit).
// ------------------------------------------------------------------
template <int ASYNC>
__global__ void __launch_bounds__(256, 2)
edge_kernel(const float* __restrict__ x, const float* __restrict__ ws, float* __restrict__ out) {
    constexpr float KSX[9] = {1, 0, -1, 2, 0, -2, 1, 0, -1};
    constexpr float KSY[9] = {1, 2, 1, 0, 0, 0, -1, -2, -1};
    constexpr float KLP[9] = {0, 1, 0, 1, -4, 1, 0, 1, 0};

    __shared__ __align__(1024) short xs[ASYNC ? 496 * 32 : 484 * XSTR];
    __shared__ __align__(16)   short ys[400 * YSTR];

    int b = blockIdx.y;
    int sel = ((const int*)ws)[WS_BIDX + b];
    if (sel == 0) return;
    int tile = blockIdx.x;
    int ty = (tile >> 4) * 16, tx = (tile & 15) * 16;
    int tid = threadIdx.x;
    int w = tid >> 6, lane = tid & 63, n = lane & 15, quad = lane >> 4;

    if constexpr (ASYNC) {
        const short* xtb = (const short*)(ws + WS_XT) + (size_t)b * (XTP * 32);
        const void* zp = (const void*)(ws + WS_ZPAD);
        for (int c = w; c < 31; c += 4) {
            int D = c * 1024 + (lane << 4);
            int L = D ^ (((D >> 7) & 7) << 4);
            int pL = L >> 6, qL = (L >> 4) & 3;
            int rr = pL / 22, cc2 = pL - rr * 22;
            bool v = (pL < 484);
            const void* src = v ? (const void*)(xtb + ((size_t)((ty + rr) * XTW + tx + cc2)) * 32 + (qL << 3)) : zp;
            gld16(src, (const void*)((const char*)xs + c * 1024));
        }
    } else {
        const float* xb = x + (size_t)b * IC * HH * WW;
        for (int p = tid; p < 484; p += 256) {
            int rr = p / 22, cc = p % 22;
            int gy = ty - 3 + rr, gx = tx - 3 + cc;
            bool v = ((unsigned)gy < HH) && ((unsigned)gx < WW);
            const float* xp = xb + gy * WW + gx;
            short* dst = xs + p * XSTR;
            #pragma unroll
            for (int ic = 0; ic < IC; ic += 4) {
                float f0 = v ? xp[(size_t)(ic + 0) * (HH * WW)] : 0.f;
                float f1 = v ? xp[(size_t)(ic + 1) * (HH * WW)] : 0.f;
                float f2 = v ? xp[(size_t)(ic + 2) * (HH * WW)] : 0.f;
                float f3 = v ? xp[(size_t)(ic + 3) * (HH * WW)] : 0.f;
                uint2 pk;
                pk.x = (unsigned int)bf16r(f0) | ((unsigned int)bf16r(f1) << 16);
                pk.y = (unsigned int)bf16r(f2) | ((unsigned int)bf16r(f3) << 16);
                *(uint2*)(dst + ic) = pk;
            }
        }
    }

    auto ldq = [&](int P, int q) -> bf16x8 {
        if constexpr (ASYNC) {
            int L = (P << 6) + (q << 4);
            int A = L ^ (((L >> 7) & 7) << 4);
            return *(const bf16x8*)((const char*)xs + A);
        } else {
            return *(const bf16x8*)(xs + P * XSTR + q * 8);
        }
    };

    int mrow0 = w * 4;
    int npass = (sel == 1) ? 2 : 1;
    f32x4 accA[4][4];
    f32x4 acc2[4][4];

    __syncthreads();

    #pragma unroll 1
    for (int pass = 0; pass < npass; pass++) {
        int kid = (sel == 1) ? pass : 2;
        if (pass) __syncthreads();

        for (int t2 = tid; t2 < 1600; t2 += 256) {
            int q = t2 & 3, px = t2 >> 2;
            int pr = px / 20, pc = px - pr * 20;
            bool inb = ((unsigned)(ty - 2 + pr) < HH) && ((unsigned)(tx - 2 + pc) < WW);
            float a[8] = {0.f, 0.f, 0.f, 0.f, 0.f, 0.f, 0.f, 0.f};
            if (inb) {
                #pragma unroll
                for (int dr = 0; dr < 3; dr++)
                    #pragma unroll
                    for (int dc = 0; dc < 3; dc++) {
                        float kv = (kid == 0) ? KSX[dr * 3 + dc]
                                 : (kid == 1) ? KSY[dr * 3 + dc]
                                              : KLP[dr * 3 + dc];
                        if (kv != 0.f) {
                            bf16x8 v = ldq((pr + dr) * 22 + pc + dc, q);
                            #pragma unroll
                            for (int j = 0; j < 8; j++)
                                a[j] += kv * bf2f((unsigned short)v[j]);
                        }
                    }
            }
            uint4 pk;
            pk.x = (unsigned int)bf16r(a[0]) | ((unsigned int)bf16r(a[1]) << 16);
            pk.y = (unsigned int)bf16r(a[2]) | ((unsigned int)bf16r(a[3]) << 16);
            pk.z = (unsigned int)bf16r(a[4]) | ((unsigned int)bf16r(a[5]) << 16);
            pk.w = (unsigned int)bf16r(a[6]) | ((unsigned int)bf16r(a[7]) << 16);
            *(uint4*)(ys + px * YSTR + q * 8) = pk;
        }
        __syncthreads();

        #pragma unroll
        for (int i = 0; i < 4; i++)
            #pragma unroll
            for (int jj = 0; jj < 4; jj++) acc2[i][jj] = (f32x4){0.f, 0.f, 0.f, 0.f};

        const bf16x8* wf = (const bf16x8*)(ws + (kid == 0 ? WS_SXWT : kid == 1 ? WS_SYWT : WS_LWT));
        bf16x8 afq[2][4];
        #pragma unroll
        for (int kp = 0; kp < 2; kp++) {
            int tn = kp * 5;
            int base = tn * 256 + lane;
            afq[kp][0] = wf[base];       afq[kp][1] = wf[base + 64];
            afq[kp][2] = wf[base + 128]; afq[kp][3] = wf[base + 192];
        }
        bf16x8 bfr2[8];
        #pragma unroll
        for (int k = 0; k < 25; k++) {
            int dw = k / 5, dh = k % 5;
            if (dh == 0) {
                #pragma unroll
                for (int rI = 0; rI < 8; rI++)
                    bfr2[rI] = *(const bf16x8*)(ys + ((mrow0 + rI) * 20 + n + dw) * YSTR + quad * 8);
            }
            #pragma unroll
            for (int r4 = 0; r4 < 4; r4++) {
                bf16x8 bb = bfr2[r4 + dh];
                acc2[r4][0] = __builtin_amdgcn_mfma_f32_16x16x32_bf16(afq[k & 1][0], bb, acc2[r4][0], 0, 0, 0);
                acc2[r4][1] = __builtin_amdgcn_mfma_f32_16x16x32_bf16(afq[k & 1][1], bb, acc2[r4][1], 0, 0, 0);
                acc2[r4][2] = __builtin_amdgcn_mfma_f32_16x16x32_bf16(afq[k & 1][2], bb, acc2[r4][2], 0, 0, 0);
                acc2[r4][3] = __builtin_amdgcn_mfma_f32_16x16x32_bf16(afq[k & 1][3], bb, acc2[r4][3], 0, 0, 0);
            }
            if (k + 2 < 25) {
                int kk = k + 2;
                int tn = (kk % 5) * 5 + (kk / 5);
                int base = tn * 256 + lane;
                afq[k & 1][0] = wf[base];       afq[k & 1][1] = wf[base + 64];
                afq[k & 1][2] = wf[base + 128]; afq[k & 1][3] = wf[base + 192];
            }
        }
        if (sel == 1 && pass == 0) {
            #pragma unroll
            for (int i = 0; i < 4; i++)
                #pragma unroll
                for (int jj = 0; jj < 4; jj++) accA[i][jj] = acc2[i][jj];
        }
    }

    float* ob = out + (size_t)b * OC * HH * WW;
    #pragma unroll
    for (int r4 = 0; r4 < 4; r4++) {
        int orow = mrow0 + r4;
        #pragma unroll
        for (int oct = 0; oct < 4; oct++) {
            #pragma unroll
            for (int r = 0; r < 4; r++) {
                int oc = oct * 16 + quad * 4 + r;
                float v;
                if (sel == 1) {
                    float vx = fmaxf(accA[r4][oct][r] + ws[WS_SXBF + oc], 0.f);
                    float vy = fmaxf(acc2[r4][oct][r] + ws[WS_SYBF + oc], 0.f);
                    v = 0.5f * (vx + vy);
                } else {
                    v = fmaxf(acc2[r4][oct][r] + ws[WS_LBF + oc], 0.f);
                }
                ob[(size_t)oc * (HH * WW) + (ty + orow) * WW + tx + n] = v;
            }
        }
    }
}

// ------------------------------------------------------------------
extern "C" void kernel_launch(void* const* d_in, const int* in_sizes, int n_in,
                              void* d_out, int out_size, void* d_ws, size_t ws_size,
                              hipStream_t stream) {
    const float* x    = (const float*)d_in[0];
    const float* gw1  = (const float*)d_in[1];
    const float* gb1  = (const float*)d_in[2];
    const float* gbn  = (const float*)d_in[3];
    const float* gw2  = (const float*)d_in[4];
    const float* gb2  = (const float*)d_in[5];
    const float* mw1  = (const float*)d_in[6];
    const float* mb1  = (const float*)d_in[7];
    const float* mbn1 = (const float*)d_in[8];
    const float* mw2  = (const float*)d_in[9];
    const float* mb2  = (const float*)d_in[10];
    const float* mbn2 = (const float*)d_in[11];
    const float* sxw  = (const float*)d_in[12];
    const float* sxb  = (const float*)d_in[13];
    const float* sxbn = (const float*)d_in[14];
    const float* syw  = (const float*)d_in[15];
    const float* syb  = (const float*)d_in[16];
    const float* sybn = (const float*)d_in[17];
    const float* lw   = (const float*)d_in[18];
    const float* lb   = (const float*)d_in[19];
    const float* lbn  = (const float*)d_in[20];
    float* ws  = (float*)d_ws;
    float* out = (float*)d_out;

    int fast  = (ws_size >= WS_NEED_FAST) ? 1 : 0;    // ~36.6 MB
    int split = (ws_size >= WS_NEED_SPLIT) ? 1 : 0;   // ~105 MB (verified engaged in R11)

    prep_kernel<<<400, 256, 0, stream>>>(mw1, mb1, mbn1, mw2, mb2, mbn2,
                                         sxw, sxb, sxbn, syw, syb, sybn, lw, lb, lbn, ws, fast, split);
    if (fast) {
        xform_kernel<<<dim3(HH, BB), 256, 0, stream>>>(x, ws);
    } else {
        gap_kernel<<<256, 256, 0, stream>>>(x, ws);
    }
    gate_kernel<<<1, 256, 0, stream>>>(gw1, gb1, gbn, gw2, gb2, ws);

    dim3 grid(256, BB);
    if (split) {
        conv1_kernel<<<grid, 256, 0, stream>>>(ws);
        conv2_kernel<<<grid, 512, 0, stream>>>(ws, out);
    } else if (fast) {
        main_kernel<1><<<grid, 256, 0, stream>>>(x, ws, out);
    } else {
        main_kernel<0><<<grid, 256, 0, stream>>>(x, ws, out);
    }
    if (fast) {
        edge_kernel<1><<<grid, 256, 0, stream>>>(x, ws, out);
    } else {
        edge_kernel<0><<<grid, 256, 0, stream>>>(x, ws, out);
    }
}

// Round 12
// 392.231 us; speedup vs baseline: 1.1669x; 1.1669x over previous
//
#include <hip/hip_runtime.h>

#define BB 8
#define IC 32
#define OC 64
#define HH 256
#define WW 256
#define EPS 1e-5f

// padded xt geometry (halo 3 top/left, 5 bottom/right; interior rows/cols 3..258)
#define XTW 264
#define XTP (XTW * XTW)      // 69696 px per batch
// padded Y geometry (conv1 output, halo 2 each side; interior 2..257)
#define YW 260
#define YP (YW * YW)         // 67600 px per batch

typedef __attribute__((ext_vector_type(8))) short bf16x8;
typedef __attribute__((ext_vector_type(4))) float f32x4;

#define YSTR 40   // fused/edge ys per-pixel stride in shorts
#define XSTR 40   // fallback xs per-pixel stride in shorts

// ---- workspace layout (float indices) ----
#define WS_GAP   0
#define WS_BIDX  256
#define WS_W1F   264                    // conv1 A-frags (bf16)
#define WS_B1F   (WS_W1F + 9216)
#define WS_W2F   (WS_B1F + 64)          // conv2 A-frags (bf16)
#define WS_B2F   (WS_W2F + 51200)
#define WS_SXWT  (WS_B2F + 64)          // edge bf16 MFMA A-frags
#define WS_SXBF  (WS_SXWT + 51200)
#define WS_SYWT  (WS_SXBF + 64)
#define WS_SYBF  (WS_SYWT + 51200)
#define WS_LWT   (WS_SYBF + 64)
#define WS_LBF   (WS_LWT + 51200)
// ---- fast-path extension ----
#define WS_XT    (WS_LBF + 64)          // 8 * 69696 px * 32ch bf16 (padded NHWC x)
#define WS_ZPAD  (WS_XT + 8921088)      // 16 floats of zeros
#define WS_NEED_FAST ((size_t)(WS_ZPAD + 16) * 4)
// ---- split-path extension (Y intermediate; verified engaged in R11) ----
#define WS_Y     (WS_ZPAD + 16)         // 8 * 67600 px * 64ch bf16 = 17305600 floats
#define WS_NEED_SPLIT ((size_t)(WS_Y + 17305600) * 4)

__device__ inline unsigned short bf16r(float f) {
    unsigned int u = __float_as_uint(f);
    unsigned int r = (u + 0x7fffu + ((u >> 16) & 1u)) >> 16;
    return (unsigned short)r;
}
__device__ inline float bf2f(unsigned short s) {
    return __uint_as_float(((unsigned int)s) << 16);
}

__device__ __forceinline__ void gld16(const void* g, const void* l) {
    __builtin_amdgcn_global_load_lds(
        (const __attribute__((address_space(1))) void*)(unsigned long long)(g),
        (__attribute__((address_space(3))) void*)(unsigned int)(unsigned long long)(l),
        16, 0, 0);
}

// ------------------------------------------------------------------
// prep: fold BN scales into weights; when split, zero Y's halo ring.
// ------------------------------------------------------------------
__global__ void prep_kernel(const float* __restrict__ mw1, const float* __restrict__ mb1, const float* __restrict__ mbn1,
                            const float* __restrict__ mw2, const float* __restrict__ mb2, const float* __restrict__ mbn2,
                            const float* __restrict__ sxw, const float* __restrict__ sxb, const float* __restrict__ sxbn,
                            const float* __restrict__ syw, const float* __restrict__ syb, const float* __restrict__ sybn,
                            const float* __restrict__ lw,  const float* __restrict__ lb,  const float* __restrict__ lbn,
                            float* __restrict__ ws, int fast, int split) {
    int idx = blockIdx.x * 256 + threadIdx.x;

    if (idx < 18432) {  // conv1 A-frags
        int j = idx & 7, lane = (idx >> 3) & 63, oct = (idx >> 9) & 1, ht = idx >> 10;
        int t = ht % 9, h = ht / 9;
        int oc = h * 32 + oct * 16 + (lane & 15);
        int ic = (lane >> 4) * 8 + j;
        float s = mbn1[oc] * rsqrtf(mbn1[192 + oc] + EPS);
        ((unsigned short*)(ws + WS_W1F))[idx] = bf16r(mw1[(oc * IC + ic) * 9 + t] * s);
    }
    if (idx < 102400) {  // conv2 A-frags
        int j = idx & 7, lane = (idx >> 3) & 63, oct = (idx >> 9) & 3, ht = idx >> 11;
        int t = ht % 25, h = ht / 25;
        int oc = oct * 16 + (lane & 15);
        int ic = h * 32 + (lane >> 4) * 8 + j;
        float s = mbn2[oc] * rsqrtf(mbn2[192 + oc] + EPS);
        ((unsigned short*)(ws + WS_W2F))[idx] = bf16r(mw2[(oc * OC + ic) * 25 + t] * s);
    }
    if (idx < 51200) {  // edge 5x5 bf16 A-frags
        int j = idx & 7, lane = (idx >> 3) & 63, oct = (idx >> 9) & 3, t = idx >> 11;
        int oc = oct * 16 + (lane & 15);
        int ic = (lane >> 4) * 8 + j;
        float ssx = sxbn[oc] * rsqrtf(sxbn[192 + oc] + EPS);
        float ssy = sybn[oc] * rsqrtf(sybn[192 + oc] + EPS);
        float sl  = lbn[oc]  * rsqrtf(lbn[192 + oc]  + EPS);
        ((unsigned short*)(ws + WS_SXWT))[idx] = bf16r(sxw[(oc * IC + ic) * 25 + t] * ssx);
        ((unsigned short*)(ws + WS_SYWT))[idx] = bf16r(syw[(oc * IC + ic) * 25 + t] * ssy);
        ((unsigned short*)(ws + WS_LWT ))[idx] = bf16r(lw [(oc * IC + ic) * 25 + t] * sl);
    }
    if (idx < 256) ws[WS_GAP + idx] = 0.f;
    if (fast && idx < 16) ws[WS_ZPAD + idx] = 0.f;
    if (split) {
        // zero Y halo: 2064 halo px/batch x 8 batches x 8 chunks = 132096
        #pragma unroll
        for (int rep = 0; rep < 2; rep++) {
            int id = idx + rep * 102400;
            if (id < 132096) {
                int bb = id / 16512, rm = id % 16512;
                int hp = rm >> 3, ch = rm & 7;
                int row, col;
                if (hp < 1040) { int rr = hp / 260; row = (rr < 2) ? rr : 256 + rr; col = hp % 260; }
                else { int j2 = hp - 1040; row = 2 + (j2 >> 2); int cv = j2 & 3; col = (cv < 2) ? cv : 256 + cv; }
                *(uint4*)((short*)(ws + WS_Y) + (((size_t)bb * YP + row * YW + col) * 64 + ch * 8)) = make_uint4(0u, 0u, 0u, 0u);
            }
        }
    }
    if (idx < 64) {
        float s1 = mbn1[idx] * rsqrtf(mbn1[192 + idx] + EPS);
        ws[WS_B1F + idx] = (mb1[idx] - mbn1[128 + idx]) * s1 + mbn1[64 + idx];
        float s2 = mbn2[idx] * rsqrtf(mbn2[192 + idx] + EPS);
        ws[WS_B2F + idx] = (mb2[idx] - mbn2[128 + idx]) * s2 + mbn2[64 + idx];
        float sx = sxbn[idx] * rsqrtf(sxbn[192 + idx] + EPS);
        ws[WS_SXBF + idx] = (sxb[idx] - sxbn[128 + idx]) * sx + sxbn[64 + idx];
        float sy = sybn[idx] * rsqrtf(sybn[192 + idx] + EPS);
        ws[WS_SYBF + idx] = (syb[idx] - sybn[128 + idx]) * sy + sybn[64 + idx];
        float sl = lbn[idx] * rsqrtf(lbn[192 + idx] + EPS);
        ws[WS_LBF + idx] = (lb[idx] - lbn[128 + idx]) * sl + lbn[64 + idx];
    }
}

// ------------------------------------------------------------------
// FAST path: NCHW fp32 -> padded NHWC bf16 xt (+ halo zeroing) + GAP.
// ------------------------------------------------------------------
__global__ void __launch_bounds__(256, 2)
xform_kernel(const float* __restrict__ x, float* __restrict__ ws) {
    int b = blockIdx.y, row = blockIdx.x, t = threadIdx.x;
    const float* xb = x + (size_t)b * (IC * HH * WW) + (size_t)row * WW;
    short* xtB = (short*)(ws + WS_XT) + (size_t)b * XTP * 32;

    unsigned int pk[16];
    #pragma unroll
    for (int k = 0; k < 32; k += 2) {
        float v0 = xb[(size_t)k * (HH * WW) + t];
        float v1 = xb[(size_t)(k + 1) * (HH * WW) + t];
        pk[k >> 1] = (unsigned int)bf16r(v0) | ((unsigned int)bf16r(v1) << 16);
    }
    uint4* dp = (uint4*)(xtB + ((size_t)(row + 3) * XTW + (t + 3)) * 32);
    dp[0] = make_uint4(pk[0],  pk[1],  pk[2],  pk[3]);
    dp[1] = make_uint4(pk[4],  pk[5],  pk[6],  pk[7]);
    dp[2] = make_uint4(pk[8],  pk[9],  pk[10], pk[11]);
    dp[3] = make_uint4(pk[12], pk[13], pk[14], pk[15]);

    if (t < 32) {
        int px = t >> 2, q = t & 3;
        int col = (px < 3) ? px : 256 + px;
        ((uint4*)(xtB + ((size_t)(row + 3) * XTW + col) * 32))[q] = make_uint4(0u, 0u, 0u, 0u);
    }
    if (row == 0) {
        for (int i = t; i < 3 * XTW * 4; i += 256) {
            int px = i >> 2, q = i & 3;
            ((uint4*)(xtB + ((size_t)(px / XTW) * XTW + (px % XTW)) * 32))[q] = make_uint4(0u, 0u, 0u, 0u);
        }
    }
    if (row == HH - 1) {
        for (int i = t; i < 5 * XTW * 4; i += 256) {
            int px = i >> 2, q = i & 3;
            ((uint4*)(xtB + ((size_t)(259 + px / XTW) * XTW + (px % XTW)) * 32))[q] = make_uint4(0u, 0u, 0u, 0u);
        }
    }

    __shared__ float gl[32];
    int w = t >> 6, lane = t & 63;
    #pragma unroll
    for (int kk = 0; kk < 8; kk++) {
        int k = w * 8 + kk;
        const float* rp = xb + (size_t)k * (HH * WW);
        float s = rp[lane] + rp[lane + 64] + rp[lane + 128] + rp[lane + 192];
        #pragma unroll
        for (int off = 32; off; off >>= 1) s += __shfl_down(s, off, 64);
        if (lane == 0) gl[k] = s;
    }
    __syncthreads();
    if (t < 32) atomicAdd(ws + WS_GAP + b * 32 + t, gl[t] * (1.f / (HH * WW)));
}

__global__ void gap_kernel(const float* __restrict__ x, float* __restrict__ ws) {
    int bc = blockIdx.x;
    const float4* p = (const float4*)(x + (size_t)bc * (HH * WW));
    float s = 0.f;
    for (int i = threadIdx.x; i < (HH * WW) / 4; i += 256) {
        float4 v = p[i];
        s += (v.x + v.y) + (v.z + v.w);
    }
    #pragma unroll
    for (int off = 32; off; off >>= 1) s += __shfl_down(s, off, 64);
    __shared__ float red[4];
    int lane = threadIdx.x & 63, w = threadIdx.x >> 6;
    if (lane == 0) red[w] = s;
    __syncthreads();
    if (threadIdx.x == 0)
        ws[WS_GAP + bc] = (red[0] + red[1] + red[2] + red[3]) * (1.f / (HH * WW));
}

__global__ void gate_kernel(const float* __restrict__ w1, const float* __restrict__ b1,
                            const float* __restrict__ gbn,
                            const float* __restrict__ w2, const float* __restrict__ b2,
                            float* __restrict__ ws) {
    __shared__ float hsh[8][32];
    int tid = threadIdx.x;
    int b = tid >> 5, j = tid & 31;
    float acc = b1[j];
    for (int i = 0; i < 32; i++) acc += ws[WS_GAP + b * 32 + i] * w1[j * 32 + i];
    float s = gbn[j] * rsqrtf(gbn[96 + j] + EPS);
    hsh[b][j] = tanhf((acc - gbn[64 + j]) * s + gbn[32 + j]);
    __syncthreads();
    if (tid < 8) {
        float best = -1e30f; int bi = 0;
        for (int c = 0; c < 3; c++) {
            float k = b2[c];
            for (int jj = 0; jj < 32; jj++) k += hsh[tid][jj] * w2[c * 32 + jj];
            if (k > best) { best = k; bi = c; }
        }
        ((int*)ws)[WS_BIDX + tid] = bi;
    }
}

// ------------------------------------------------------------------
// SPLIT pass 1: conv1 3x3+bn+relu -> padded Y (bf16 NHWC). (R11-verified.)
// ------------------------------------------------------------------
__global__ void __launch_bounds__(256, 2)
conv1_kernel(float* __restrict__ ws) {
    __shared__ __align__(1024) short xs[10752];   // 21504 B (324 px * 64B + pad)

    int b = blockIdx.y;
    if (((const int*)ws)[WS_BIDX + b] != 0) return;
    int tile = blockIdx.x;
    int ty = (tile >> 4) * 16, tx = (tile & 15) * 16;
    int tid = threadIdx.x;
    int w = tid >> 6, lane = tid & 63, n = lane & 15, quad = lane >> 4;

    const short* xtb = (const short*)(ws + WS_XT) + (size_t)b * (XTP * 32);
    for (int c = w; c < 21; c += 4) {
        int D = c * 1024 + (lane << 4);
        int L = D ^ (((D >> 7) & 7) << 4);
        int pL = L >> 6, qL = (L >> 4) & 3;
        int rr = pL / 18, cc2 = pL - rr * 18;
        if (pL >= 324) { rr = 0; cc2 = 0; }   // tail chunks: harmless refetch
        const void* src = (const void*)(xtb + ((size_t)((ty + 2 + rr) * XTW + tx + 2 + cc2)) * 32 + (qL << 3));
        gld16(src, (const void*)((const char*)xs + c * 1024));
    }

    auto ldb = [&](int r, int c) -> bf16x8 {
        int L = ((r * 18 + c) << 6) + (quad << 4);
        int A = L ^ (((L >> 7) & 7) << 4);
        return *(const bf16x8*)((const char*)xs + A);
    };

    const short* w1v = (const short*)(ws + WS_W1F);
    short* Yb = (short*)(ws + WS_Y) + (size_t)b * ((size_t)YP * 64);

    f32x4 a1[4][4];
    #pragma unroll
    for (int i = 0; i < 4; i++)
        #pragma unroll
        for (int jj = 0; jj < 4; jj++) a1[i][jj] = (f32x4){0.f, 0.f, 0.f, 0.f};

    int R0 = w * 4;

    __syncthreads();  // xs staged (drains vmcnt)

    #pragma unroll
    for (int dw = 0; dw < 3; dw++) {
        bf16x8 w1f[3][4];
        #pragma unroll
        for (int dh = 0; dh < 3; dh++) {
            int t = dh * 3 + dw;
            #pragma unroll
            for (int o4 = 0; o4 < 4; o4++)
                w1f[dh][o4] = *(const bf16x8*)(w1v + (((((o4 >> 1) * 9 + t) * 2) + (o4 & 1)) * 64 + lane) * 8);
        }
        bf16x8 bfr[6];
        #pragma unroll
        for (int rI = 0; rI < 6; rI++)
            bfr[rI] = ldb(R0 + rI, n + dw);
        #pragma unroll
        for (int dh = 0; dh < 3; dh++)
            #pragma unroll
            for (int r4 = 0; r4 < 4; r4++) {
                #pragma unroll
                for (int o4 = 0; o4 < 4; o4++)
                    a1[r4][o4] = __builtin_amdgcn_mfma_f32_16x16x32_bf16(w1f[dh][o4], bfr[r4 + dh], a1[r4][o4], 0, 0, 0);
            }
    }

    #pragma unroll
    for (int o4 = 0; o4 < 4; o4++) {
        float bias1[4];
        #pragma unroll
        for (int r = 0; r < 4; r++)
            bias1[r] = ws[WS_B1F + o4 * 16 + quad * 4 + r];
        #pragma unroll
        for (int r4 = 0; r4 < 4; r4++) {
            float v0 = fmaxf(a1[r4][o4][0] + bias1[0], 0.f);
            float v1 = fmaxf(a1[r4][o4][1] + bias1[1], 0.f);
            float v2 = fmaxf(a1[r4][o4][2] + bias1[2], 0.f);
            float v3 = fmaxf(a1[r4][o4][3] + bias1[3], 0.f);
            uint2 pkk;
            pkk.x = (unsigned int)bf16r(v0) | ((unsigned int)bf16r(v1) << 16);
            pkk.y = (unsigned int)bf16r(v2) | ((unsigned int)bf16r(v3) << 16);
            int row = ty + R0 + r4 + 2, col = tx + n + 2;
            *(uint2*)(Yb + ((size_t)(row * YW + col)) * 64 + o4 * 16 + quad * 4) = pkk;
        }
    }
}

// ------------------------------------------------------------------
// SPLIT pass 2: conv2 5x5+bn+relu from padded Y. Stage 20x20x64ch tile
// (51.2KB, swizzled), then 800 MFMA/wave with ZERO barriers after staging.
// R14: reverted to the R11-verified configuration (256 thr, (256,2),
// afq[4][4] 4-deep ring, acc2[4][4]) — measured 115us / MfmaUtil 39 /
// 0 bank conflicts. R12 (2-deep ring: VGPR stayed 112, flat) and R13
// (oc-split: halved MFMA per latency chain, 182us) both lost; this is
// the best measured point on the latency:work curve.
// ------------------------------------------------------------------
__global__ void __launch_bounds__(256, 2)
conv2_kernel(const float* __restrict__ ws, float* __restrict__ out) {
    __shared__ __align__(1024) short ysl[25600];   // 51200 B (400 px * 128B)

    int b = blockIdx.y;
    if (((const int*)ws)[WS_BIDX + b] != 0) return;
    int tile = blockIdx.x;
    int ty = (tile >> 4) * 16, tx = (tile & 15) * 16;
    int tid = threadIdx.x;
    int w = tid >> 6, lane = tid & 63, n = lane & 15, quad = lane >> 4;

    const short* Yb = (const short*)(ws + WS_Y) + (size_t)b * ((size_t)YP * 64);
    for (int c = w; c < 50; c += 4) {
        int D = c * 1024 + (lane << 4);
        int L = D ^ (((D >> 7) & 7) << 4);
        int pL = L >> 7, sub = (L >> 4) & 7;
        int rr = pL / 20, cc2 = pL - rr * 20;
        const void* src = (const void*)(Yb + ((size_t)((ty + rr) * YW + tx + cc2)) * 64 + (sub << 3));
        gld16(src, (const void*)((const char*)ysl + c * 1024));
    }

    auto ldy = [&](int px, int h) -> bf16x8 {
        int L = (px << 7) + (h << 6) + (quad << 4);
        int A = L ^ (((L >> 7) & 7) << 4);
        return *(const bf16x8*)((const char*)ysl + A);
    };

    const bf16x8* w2v = (const bf16x8*)(ws + WS_W2F);

    f32x4 acc2[4][4];
    #pragma unroll
    for (int i = 0; i < 4; i++)
        #pragma unroll
        for (int jj = 0; jj < 4; jj++) acc2[i][jj] = (f32x4){0.f, 0.f, 0.f, 0.f};
    int mrow0 = w * 4;

    __syncthreads();  // ysl staged (drains vmcnt) — the ONLY barrier

    #pragma unroll 1
    for (int h = 0; h < 2; h++) {
        const bf16x8* w2h = w2v + (size_t)h * 100 * 64;
        bf16x8 afq[4][4];
        #pragma unroll
        for (int kp = 0; kp < 4; kp++) {
            int tn = (kp % 5) * 5 + (kp / 5);
            int base = tn * 256 + lane;
            afq[kp][0] = w2h[base];       afq[kp][1] = w2h[base + 64];
            afq[kp][2] = w2h[base + 128]; afq[kp][3] = w2h[base + 192];
        }
        bf16x8 bfr2[8];
        #pragma unroll
        for (int k = 0; k < 25; k++) {
            int dw = k / 5, dh = k % 5;
            if (dh == 0) {
                #pragma unroll
                for (int rI = 0; rI < 8; rI++)
                    bfr2[rI] = ldy((mrow0 + rI) * 20 + n + dw, h);
            }
            #pragma unroll
            for (int r4 = 0; r4 < 4; r4++) {
                bf16x8 bb = bfr2[r4 + dh];
                acc2[r4][0] = __builtin_amdgcn_mfma_f32_16x16x32_bf16(afq[k & 3][0], bb, acc2[r4][0], 0, 0, 0);
                acc2[r4][1] = __builtin_amdgcn_mfma_f32_16x16x32_bf16(afq[k & 3][1], bb, acc2[r4][1], 0, 0, 0);
                acc2[r4][2] = __builtin_amdgcn_mfma_f32_16x16x32_bf16(afq[k & 3][2], bb, acc2[r4][2], 0, 0, 0);
                acc2[r4][3] = __builtin_amdgcn_mfma_f32_16x16x32_bf16(afq[k & 3][3], bb, acc2[r4][3], 0, 0, 0);
            }
            if (k + 4 < 25) {
                int kk = k + 4;
                int tn = (kk % 5) * 5 + (kk / 5);
                int base = tn * 256 + lane;
                afq[k & 3][0] = w2h[base];       afq[k & 3][1] = w2h[base + 64];
                afq[k & 3][2] = w2h[base + 128]; afq[k & 3][3] = w2h[base + 192];
            }
        }
    }

    float bias2[4][4];
    #pragma unroll
    for (int oct = 0; oct < 4; oct++)
        #pragma unroll
        for (int r = 0; r < 4; r++)
            bias2[oct][r] = ws[WS_B2F + oct * 16 + quad * 4 + r];

    float* ob = out + (size_t)b * OC * HH * WW;
    #pragma unroll
    for (int r4 = 0; r4 < 4; r4++) {
        int orow = mrow0 + r4;
        #pragma unroll
        for (int oct = 0; oct < 4; oct++) {
            #pragma unroll
            for (int r = 0; r < 4; r++) {
                int oc = oct * 16 + quad * 4 + r;
                float v = fmaxf(acc2[r4][oct][r] + bias2[oct][r], 0.f);
                ob[(size_t)oc * (HH * WW) + (ty + orow) * WW + tx + n] = v;
            }
        }
    }
}

// ------------------------------------------------------------------
// FUSED main (tier-2/3 fallback; R6-verified body).
// ------------------------------------------------------------------
template <int ASYNC>
__global__ void __launch_bounds__(256, 2)
main_kernel(const float* __restrict__ x, const float* __restrict__ ws, float* __restrict__ out) {
    __shared__ __align__(1024) short xs[ASYNC ? 496 * 32 : 484 * XSTR];
    __shared__ __align__(16)   short ys[400 * YSTR];

    int b = blockIdx.y;
    if (((const int*)ws)[WS_BIDX + b] != 0) return;
    int tile = blockIdx.x;
    int ty = (tile >> 4) * 16, tx = (tile & 15) * 16;
    int tid = threadIdx.x;
    int w = tid >> 6, lane = tid & 63, n = lane & 15, quad = lane >> 4;

    if constexpr (ASYNC) {
        const short* xtb = (const short*)(ws + WS_XT) + (size_t)b * (XTP * 32);
        for (int c = w; c < 31; c += 4) {
            int D = c * 1024 + (lane << 4);
            int L = D ^ (((D >> 7) & 7) << 4);
            int pL = L >> 6, qL = (L >> 4) & 3;
            int rr = pL / 22, cc2 = pL - rr * 22;
            if (pL >= 484) { rr = 21; cc2 = 21; }
            const void* src = (const void*)(xtb + ((size_t)((ty + rr) * XTW + tx + cc2)) * 32 + (qL << 3));
            gld16(src, (const void*)((const char*)xs + c * 1024));
        }
    } else {
        const float* xb = x + (size_t)b * IC * HH * WW;
        for (int p = tid; p < 484; p += 256) {
            int rr = p / 22, cc = p % 22;
            int gy = ty - 3 + rr, gx = tx - 3 + cc;
            bool v = ((unsigned)gy < HH) && ((unsigned)gx < WW);
            const float* xp = xb + gy * WW + gx;
            short* dst = xs + p * XSTR;
            #pragma unroll
            for (int ic = 0; ic < IC; ic += 4) {
                float f0 = v ? xp[(size_t)(ic + 0) * (HH * WW)] : 0.f;
                float f1 = v ? xp[(size_t)(ic + 1) * (HH * WW)] : 0.f;
                float f2 = v ? xp[(size_t)(ic + 2) * (HH * WW)] : 0.f;
                float f3 = v ? xp[(size_t)(ic + 3) * (HH * WW)] : 0.f;
                uint2 pk;
                pk.x = (unsigned int)bf16r(f0) | ((unsigned int)bf16r(f1) << 16);
                pk.y = (unsigned int)bf16r(f2) | ((unsigned int)bf16r(f3) << 16);
                *(uint2*)(dst + ic) = pk;
            }
        }
    }

    auto ldb = [&](int P) -> bf16x8 {
        if constexpr (ASYNC) {
            int L = (P << 6) + (quad << 4);
            int A = L ^ (((L >> 7) & 7) << 4);
            return *(const bf16x8*)((const char*)xs + A);
        } else {
            return *(const bf16x8*)(xs + P * XSTR + quad * 8);
        }
    };

    const short* w1v = (const short*)(ws + WS_W1F);
    const bf16x8* w2v = (const bf16x8*)(ws + WS_W2F);

    f32x4 acc2[4][4];
    #pragma unroll
    for (int i = 0; i < 4; i++)
        #pragma unroll
        for (int jj = 0; jj < 4; jj++) acc2[i][jj] = (f32x4){0.f, 0.f, 0.f, 0.f};
    int mrow0 = w * 4;
    int yr0   = w * 5;

    __syncthreads();

    #pragma unroll 1
    for (int h = 0; h < 2; h++) {
        if (h) __syncthreads();

        #pragma unroll
        for (int cg = 0; cg < 2; cg++) {
            int cb = cg * 4;
            f32x4 a1[5][2];
            #pragma unroll
            for (int rr = 0; rr < 5; rr++) {
                a1[rr][0] = (f32x4){0.f, 0.f, 0.f, 0.f};
                a1[rr][1] = (f32x4){0.f, 0.f, 0.f, 0.f};
            }
            #pragma unroll
            for (int dw = 0; dw < 3; dw++) {
                bf16x8 w1f[3][2];
                #pragma unroll
                for (int dh = 0; dh < 3; dh++) {
                    int t = dh * 3 + dw;
                    w1f[dh][0] = *(const bf16x8*)(w1v + (((h * 9 + t) * 2 + 0) * 64 + lane) * 8);
                    w1f[dh][1] = *(const bf16x8*)(w1v + (((h * 9 + t) * 2 + 1) * 64 + lane) * 8);
                }
                bf16x8 bfr[7];
                #pragma unroll
                for (int rI = 0; rI < 7; rI++)
                    bfr[rI] = ldb((yr0 + rI) * 22 + cb + n + dw);
                #pragma unroll
                for (int dh = 0; dh < 3; dh++)
                    #pragma unroll
                    for (int rr = 0; rr < 5; rr++) {
                        a1[rr][0] = __builtin_amdgcn_mfma_f32_16x16x32_bf16(w1f[dh][0], bfr[rr + dh], a1[rr][0], 0, 0, 0);
                        a1[rr][1] = __builtin_amdgcn_mfma_f32_16x16x32_bf16(w1f[dh][1], bfr[rr + dh], a1[rr][1], 0, 0, 0);
                    }
            }
            #pragma unroll
            for (int oct = 0; oct < 2; oct++) {
                float bias1[4];
                #pragma unroll
                for (int r = 0; r < 4; r++)
                    bias1[r] = ws[WS_B1F + h * 32 + oct * 16 + quad * 4 + r];
                #pragma unroll
                for (int rr = 0; rr < 5; rr++) {
                    int yr = yr0 + rr;
                    int gy2 = ty - 2 + yr, gx2 = tx - 2 + cb + n;
                    bool inb = ((unsigned)gy2 < HH) && ((unsigned)gx2 < WW);
                    float v0 = inb ? fmaxf(a1[rr][oct][0] + bias1[0], 0.f) : 0.f;
                    float v1 = inb ? fmaxf(a1[rr][oct][1] + bias1[1], 0.f) : 0.f;
                    float v2 = inb ? fmaxf(a1[rr][oct][2] + bias1[2], 0.f) : 0.f;
                    float v3 = inb ? fmaxf(a1[rr][oct][3] + bias1[3], 0.f) : 0.f;
                    uint2 pkk;
                    pkk.x = (unsigned int)bf16r(v0) | ((unsigned int)bf16r(v1) << 16);
                    pkk.y = (unsigned int)bf16r(v2) | ((unsigned int)bf16r(v3) << 16);
                    *(uint2*)(ys + (yr * 20 + cb + n) * YSTR + oct * 16 + quad * 4) = pkk;
                }
            }
        }
        __syncthreads();

        const bf16x8* w2h = w2v + (size_t)h * 100 * 64;
        bf16x8 afq[4][4];
        #pragma unroll
        for (int kp = 0; kp < 4; kp++) {
            int tn = (kp % 5) * 5 + (kp / 5);
            int base = tn * 256 + lane;
            afq[kp][0] = w2h[base];       afq[kp][1] = w2h[base + 64];
            afq[kp][2] = w2h[base + 128]; afq[kp][3] = w2h[base + 192];
        }
        bf16x8 bfr2[8];
        #pragma unroll
        for (int k = 0; k < 25; k++) {
            int dw = k / 5, dh = k % 5;
            if (dh == 0) {
                #pragma unroll
                for (int rI = 0; rI < 8; rI++)
                    bfr2[rI] = *(const bf16x8*)(ys + ((mrow0 + rI) * 20 + n + dw) * YSTR + quad * 8);
            }
            #pragma unroll
            for (int r4 = 0; r4 < 4; r4++) {
                bf16x8 bb = bfr2[r4 + dh];
                acc2[r4][0] = __builtin_amdgcn_mfma_f32_16x16x32_bf16(afq[k & 3][0], bb, acc2[r4][0], 0, 0, 0);
                acc2[r4][1] = __builtin_amdgcn_mfma_f32_16x16x32_bf16(afq[k & 3][1], bb, acc2[r4][1], 0, 0, 0);
                acc2[r4][2] = __builtin_amdgcn_mfma_f32_16x16x32_bf16(afq[k & 3][2], bb, acc2[r4][2], 0, 0, 0);
                acc2[r4][3] = __builtin_amdgcn_mfma_f32_16x16x32_bf16(afq[k & 3][3], bb, acc2[r4][3], 0, 0, 0);
            }
            if (k + 4 < 25) {
                int kk = k + 4;
                int tn = (kk % 5) * 5 + (kk / 5);
                int base = tn * 256 + lane;
                afq[k & 3][0] = w2h[base];       afq[k & 3][1] = w2h[base + 64];
                afq[k & 3][2] = w2h[base + 128]; afq[k & 3][3] = w2h[base + 192];
            }
        }
    }

    float bias2[4][4];
    #pragma unroll
    for (int oct = 0; oct < 4; oct++)
        #pragma unroll
        for (int r = 0; r < 4; r++)
            bias2[oct][r] = ws[WS_B2F + oct * 16 + quad * 4 + r];

    float* ob = out + (size_t)b * OC * HH * WW;
    #pragma unroll
    for (int r4 = 0; r4 < 4; r4++) {
        int orow = mrow0 + r4;
        #pragma unroll
        for (int oct = 0; oct < 4; oct++) {
            #pragma unroll
            for (int r = 0; r < 4; r++) {
                int oc = oct * 16 + quad * 4 + r;
                float v = fmaxf(acc2[r4][oct][r] + bias2[oct][r], 0.f);
                ob[(size_t)oc * (HH * WW) + (ty + orow) * WW + tx + n] = v;
            }
        }
    }
}

// ------------------------------------------------------------------
// edge branches via MFMA (R8-verified padded-xt staging; early-exit).
// ------------------------------------------------------------------
template <int ASYNC>
__global__ void __launch_bounds__(256, 2)
edge_kernel(const float* __restrict__ x, const float* __restrict__ ws, float* __restrict__ out) {
    constexpr float KSX[9] = {1, 0, -1, 2, 0, -2, 1, 0, -1};
    constexpr float KSY[9] = {1, 2, 1, 0, 0, 0, -1, -2, -1};
    constexpr float KLP[9] = {0, 1, 0, 1, -4, 1, 0, 1, 0};

    __shared__ __align__(1024) short xs[ASYNC ? 496 * 32 : 484 * XSTR];
    __shared__ __align__(16)   short ys[400 * YSTR];

    int b = blockIdx.y;
    int sel = ((const int*)ws)[WS_BIDX + b];
    if (sel == 0) return;
    int tile = blockIdx.x;
    int ty = (tile >> 4) * 16, tx = (tile & 15) * 16;
    int tid = threadIdx.x;
    int w = tid >> 6, lane = tid & 63, n = lane & 15, quad = lane >> 4;

    if constexpr (ASYNC) {
        const short* xtb = (const short*)(ws + WS_XT) + (size_t)b * (XTP * 32);
        const void* zp = (const void*)(ws + WS_ZPAD);
        for (int c = w; c < 31; c += 4) {
            int D = c * 1024 + (lane << 4);
            int L = D ^ (((D >> 7) & 7) << 4);
            int pL = L >> 6, qL = (L >> 4) & 3;
            int rr = pL / 22, cc2 = pL - rr * 22;
            bool v = (pL < 484);
            const void* src = v ? (const void*)(xtb + ((size_t)((ty + rr) * XTW + tx + cc2)) * 32 + (qL << 3)) : zp;
            gld16(src, (const void*)((const char*)xs + c * 1024));
        }
    } else {
        const float* xb = x + (size_t)b * IC * HH * WW;
        for (int p = tid; p < 484; p += 256) {
            int rr = p / 22, cc = p % 22;
            int gy = ty - 3 + rr, gx = tx - 3 + cc;
            bool v = ((unsigned)gy < HH) && ((unsigned)gx < WW);
            const float* xp = xb + gy * WW + gx;
            short* dst = xs + p * XSTR;
            #pragma unroll
            for (int ic = 0; ic < IC; ic += 4) {
                float f0 = v ? xp[(size_t)(ic + 0) * (HH * WW)] : 0.f;
                float f1 = v ? xp[(size_t)(ic + 1) * (HH * WW)] : 0.f;
                float f2 = v ? xp[(size_t)(ic + 2) * (HH * WW)] : 0.f;
                float f3 = v ? xp[(size_t)(ic + 3) * (HH * WW)] : 0.f;
                uint2 pk;
                pk.x = (unsigned int)bf16r(f0) | ((unsigned int)bf16r(f1) << 16);
                pk.y = (unsigned int)bf16r(f2) | ((unsigned int)bf16r(f3) << 16);
                *(uint2*)(dst + ic) = pk;
            }
        }
    }

    auto ldq = [&](int P, int q) -> bf16x8 {
        if constexpr (ASYNC) {
            int L = (P << 6) + (q << 4);
            int A = L ^ (((L >> 7) & 7) << 4);
            return *(const bf16x8*)((const char*)xs + A);
        } else {
            return *(const bf16x8*)(xs + P * XSTR + q * 8);
        }
    };

    int mrow0 = w * 4;
    int npass = (sel == 1) ? 2 : 1;
    f32x4 accA[4][4];
    f32x4 acc2[4][4];

    __syncthreads();

    #pragma unroll 1
    for (int pass = 0; pass < npass; pass++) {
        int kid = (sel == 1) ? pass : 2;
        if (pass) __syncthreads();

        for (int t2 = tid; t2 < 1600; t2 += 256) {
            int q = t2 & 3, px = t2 >> 2;
            int pr = px / 20, pc = px - pr * 20;
            bool inb = ((unsigned)(ty - 2 + pr) < HH) && ((unsigned)(tx - 2 + pc) < WW);
            float a[8] = {0.f, 0.f, 0.f, 0.f, 0.f, 0.f, 0.f, 0.f};
            if (inb) {
                #pragma unroll
                for (int dr = 0; dr < 3; dr++)
                    #pragma unroll
                    for (int dc = 0; dc < 3; dc++) {
                        float kv = (kid == 0) ? KSX[dr * 3 + dc]
                                 : (kid == 1) ? KSY[dr * 3 + dc]
                                              : KLP[dr * 3 + dc];
                        if (kv != 0.f) {
                            bf16x8 v = ldq((pr + dr) * 22 + pc + dc, q);
                            #pragma unroll
                            for (int j = 0; j < 8; j++)
                                a[j] += kv * bf2f((unsigned short)v[j]);
                        }
                    }
            }
            uint4 pk;
            pk.x = (unsigned int)bf16r(a[0]) | ((unsigned int)bf16r(a[1]) << 16);
            pk.y = (unsigned int)bf16r(a[2]) | ((unsigned int)bf16r(a[3]) << 16);
            pk.z = (unsigned int)bf16r(a[4]) | ((unsigned int)bf16r(a[5]) << 16);
            pk.w = (unsigned int)bf16r(a[6]) | ((unsigned int)bf16r(a[7]) << 16);
            *(uint4*)(ys + px * YSTR + q * 8) = pk;
        }
        __syncthreads();

        #pragma unroll
        for (int i = 0; i < 4; i++)
            #pragma unroll
            for (int jj = 0; jj < 4; jj++) acc2[i][jj] = (f32x4){0.f, 0.f, 0.f, 0.f};

        const bf16x8* wf = (const bf16x8*)(ws + (kid == 0 ? WS_SXWT : kid == 1 ? WS_SYWT : WS_LWT));
        bf16x8 afq[2][4];
        #pragma unroll
        for (int kp = 0; kp < 2; kp++) {
            int tn = kp * 5;
            int base = tn * 256 + lane;
            afq[kp][0] = wf[base];       afq[kp][1] = wf[base + 64];
            afq[kp][2] = wf[base + 128]; afq[kp][3] = wf[base + 192];
        }
        bf16x8 bfr2[8];
        #pragma unroll
        for (int k = 0; k < 25; k++) {
            int dw = k / 5, dh = k % 5;
            if (dh == 0) {
                #pragma unroll
                for (int rI = 0; rI < 8; rI++)
                    bfr2[rI] = *(const bf16x8*)(ys + ((mrow0 + rI) * 20 + n + dw) * YSTR + quad * 8);
            }
            #pragma unroll
            for (int r4 = 0; r4 < 4; r4++) {
                bf16x8 bb = bfr2[r4 + dh];
                acc2[r4][0] = __builtin_amdgcn_mfma_f32_16x16x32_bf16(afq[k & 1][0], bb, acc2[r4][0], 0, 0, 0);
                acc2[r4][1] = __builtin_amdgcn_mfma_f32_16x16x32_bf16(afq[k & 1][1], bb, acc2[r4][1], 0, 0, 0);
                acc2[r4][2] = __builtin_amdgcn_mfma_f32_16x16x32_bf16(afq[k & 1][2], bb, acc2[r4][2], 0, 0, 0);
                acc2[r4][3] = __builtin_amdgcn_mfma_f32_16x16x32_bf16(afq[k & 1][3], bb, acc2[r4][3], 0, 0, 0);
            }
            if (k + 2 < 25) {
                int kk = k + 2;
                int tn = (kk % 5) * 5 + (kk / 5);
                int base = tn * 256 + lane;
                afq[k & 1][0] = wf[base];       afq[k & 1][1] = wf[base + 64];
                afq[k & 1][2] = wf[base + 128]; afq[k & 1][3] = wf[base + 192];
            }
        }
        if (sel == 1 && pass == 0) {
            #pragma unroll
            for (int i = 0; i < 4; i++)
                #pragma unroll
                for (int jj = 0; jj < 4; jj++) accA[i][jj] = acc2[i][jj];
        }
    }

    float* ob = out + (size_t)b * OC * HH * WW;
    #pragma unroll
    for (int r4 = 0; r4 < 4; r4++) {
        int orow = mrow0 + r4;
        #pragma unroll
        for (int oct = 0; oct < 4; oct++) {
            #pragma unroll
            for (int r = 0; r < 4; r++) {
                int oc = oct * 16 + quad * 4 + r;
                float v;
                if (sel == 1) {
                    float vx = fmaxf(accA[r4][oct][r] + ws[WS_SXBF + oc], 0.f);
                    float vy = fmaxf(acc2[r4][oct][r] + ws[WS_SYBF + oc], 0.f);
                    v = 0.5f * (vx + vy);
                } else {
                    v = fmaxf(acc2[r4][oct][r] + ws[WS_LBF + oc], 0.f);
                }
                ob[(size_t)oc * (HH * WW) + (ty + orow) * WW + tx + n] = v;
            }
        }
    }
}

// ------------------------------------------------------------------
extern "C" void kernel_launch(void* const* d_in, const int* in_sizes, int n_in,
                              void* d_out, int out_size, void* d_ws, size_t ws_size,
                              hipStream_t stream) {
    const float* x    = (const float*)d_in[0];
    const float* gw1  = (const float*)d_in[1];
    const float* gb1  = (const float*)d_in[2];
    const float* gbn  = (const float*)d_in[3];
    const float* gw2  = (const float*)d_in[4];
    const float* gb2  = (const float*)d_in[5];
    const float* mw1  = (const float*)d_in[6];
    const float* mb1  = (const float*)d_in[7];
    const float* mbn1 = (const float*)d_in[8];
    const float* mw2  = (const float*)d_in[9];
    const float* mb2  = (const float*)d_in[10];
    const float* mbn2 = (const float*)d_in[11];
    const float* sxw  = (const float*)d_in[12];
    const float* sxb  = (const float*)d_in[13];
    const float* sxbn = (const float*)d_in[14];
    const float* syw  = (const float*)d_in[15];
    const float* syb  = (const float*)d_in[16];
    const float* sybn = (const float*)d_in[17];
    const float* lw   = (const float*)d_in[18];
    const float* lb   = (const float*)d_in[19];
    const float* lbn  = (const float*)d_in[20];
    float* ws  = (float*)d_ws;
    float* out = (float*)d_out;

    int fast  = (ws_size >= WS_NEED_FAST) ? 1 : 0;    // ~36.6 MB
    int split = (ws_size >= WS_NEED_SPLIT) ? 1 : 0;   // ~105 MB (verified engaged in R11)

    prep_kernel<<<400, 256, 0, stream>>>(mw1, mb1, mbn1, mw2, mb2, mbn2,
                                         sxw, sxb, sxbn, syw, syb, sybn, lw, lb, lbn, ws, fast, split);
    if (fast) {
        xform_kernel<<<dim3(HH, BB), 256, 0, stream>>>(x, ws);
    } else {
        gap_kernel<<<256, 256, 0, stream>>>(x, ws);
    }
    gate_kernel<<<1, 256, 0, stream>>>(gw1, gb1, gbn, gw2, gb2, ws);

    dim3 grid(256, BB);
    if (split) {
        conv1_kernel<<<grid, 256, 0, stream>>>(ws);
        conv2_kernel<<<grid, 256, 0, stream>>>(ws, out);
    } else if (fast) {
        main_kernel<1><<<grid, 256, 0, stream>>>(x, ws, out);
    } else {
        main_kernel<0><<<grid, 256, 0, stream>>>(x, ws, out);
    }
    if (fast) {
        edge_kernel<1><<<grid, 256, 0, stream>>>(x, ws, out);
    } else {
        edge_kernel<0><<<grid, 256, 0, stream>>>(x, ws, out);
    }
}

// Round 13
// 365.536 us; speedup vs baseline: 1.2521x; 1.0730x over previous
//
#include <hip/hip_runtime.h>

#define BB 8
#define IC 32
#define OC 64
#define HH 256
#define WW 256
#define EPS 1e-5f

// padded xt geometry (halo 3 top/left, 5 bottom/right; interior rows/cols 3..258)
#define XTW 264
#define XTP (XTW * XTW)      // 69696 px per batch
// padded Y geometry (conv1 output, halo 2 each side; interior 2..257)
#define YW 260
#define YP (YW * YW)         // 67600 px per batch

typedef __attribute__((ext_vector_type(8))) short bf16x8;
typedef __attribute__((ext_vector_type(4))) float f32x4;

#define YSTR 40   // fused/edge ys per-pixel stride in shorts
#define XSTR 40   // fallback xs per-pixel stride in shorts

// ---- workspace layout (float indices) ----
#define WS_GAP   0
#define WS_BIDX  256
#define WS_W1F   264                    // conv1 A-frags (bf16)
#define WS_B1F   (WS_W1F + 9216)
#define WS_W2F   (WS_B1F + 64)          // conv2 A-frags (bf16)
#define WS_B2F   (WS_W2F + 51200)
#define WS_SXWT  (WS_B2F + 64)          // edge bf16 MFMA A-frags
#define WS_SXBF  (WS_SXWT + 51200)
#define WS_SYWT  (WS_SXBF + 64)
#define WS_SYBF  (WS_SYWT + 51200)
#define WS_LWT   (WS_SYBF + 64)
#define WS_LBF   (WS_LWT + 51200)
// ---- fast-path extension ----
#define WS_XT    (WS_LBF + 64)          // 8 * 69696 px * 32ch bf16 (padded NHWC x)
#define WS_ZPAD  (WS_XT + 8921088)      // 16 floats of zeros
#define WS_NEED_FAST ((size_t)(WS_ZPAD + 16) * 4)
// ---- split-path extension (Y intermediate; verified engaged in R11) ----
#define WS_Y     (WS_ZPAD + 16)         // 8 * 67600 px * 64ch bf16 = 17305600 floats
#define WS_NEED_SPLIT ((size_t)(WS_Y + 17305600) * 4)

__device__ inline unsigned short bf16r(float f) {
    unsigned int u = __float_as_uint(f);
    unsigned int r = (u + 0x7fffu + ((u >> 16) & 1u)) >> 16;
    return (unsigned short)r;
}
__device__ inline float bf2f(unsigned short s) {
    return __uint_as_float(((unsigned int)s) << 16);
}

__device__ __forceinline__ void gld16(const void* g, const void* l) {
    __builtin_amdgcn_global_load_lds(
        (const __attribute__((address_space(1))) void*)(unsigned long long)(g),
        (__attribute__((address_space(3))) void*)(unsigned int)(unsigned long long)(l),
        16, 0, 0);
}

// ------------------------------------------------------------------
// prep: fold BN scales into weights; when split, zero Y's halo ring.
// ------------------------------------------------------------------
__global__ void prep_kernel(const float* __restrict__ mw1, const float* __restrict__ mb1, const float* __restrict__ mbn1,
                            const float* __restrict__ mw2, const float* __restrict__ mb2, const float* __restrict__ mbn2,
                            const float* __restrict__ sxw, const float* __restrict__ sxb, const float* __restrict__ sxbn,
                            const float* __restrict__ syw, const float* __restrict__ syb, const float* __restrict__ sybn,
                            const float* __restrict__ lw,  const float* __restrict__ lb,  const float* __restrict__ lbn,
                            float* __restrict__ ws, int fast, int split) {
    int idx = blockIdx.x * 256 + threadIdx.x;

    if (idx < 18432) {  // conv1 A-frags
        int j = idx & 7, lane = (idx >> 3) & 63, oct = (idx >> 9) & 1, ht = idx >> 10;
        int t = ht % 9, h = ht / 9;
        int oc = h * 32 + oct * 16 + (lane & 15);
        int ic = (lane >> 4) * 8 + j;
        float s = mbn1[oc] * rsqrtf(mbn1[192 + oc] + EPS);
        ((unsigned short*)(ws + WS_W1F))[idx] = bf16r(mw1[(oc * IC + ic) * 9 + t] * s);
    }
    if (idx < 102400) {  // conv2 A-frags
        int j = idx & 7, lane = (idx >> 3) & 63, oct = (idx >> 9) & 3, ht = idx >> 11;
        int t = ht % 25, h = ht / 25;
        int oc = oct * 16 + (lane & 15);
        int ic = h * 32 + (lane >> 4) * 8 + j;
        float s = mbn2[oc] * rsqrtf(mbn2[192 + oc] + EPS);
        ((unsigned short*)(ws + WS_W2F))[idx] = bf16r(mw2[(oc * OC + ic) * 25 + t] * s);
    }
    if (idx < 51200) {  // edge 5x5 bf16 A-frags
        int j = idx & 7, lane = (idx >> 3) & 63, oct = (idx >> 9) & 3, t = idx >> 11;
        int oc = oct * 16 + (lane & 15);
        int ic = (lane >> 4) * 8 + j;
        float ssx = sxbn[oc] * rsqrtf(sxbn[192 + oc] + EPS);
        float ssy = sybn[oc] * rsqrtf(sybn[192 + oc] + EPS);
        float sl  = lbn[oc]  * rsqrtf(lbn[192 + oc]  + EPS);
        ((unsigned short*)(ws + WS_SXWT))[idx] = bf16r(sxw[(oc * IC + ic) * 25 + t] * ssx);
        ((unsigned short*)(ws + WS_SYWT))[idx] = bf16r(syw[(oc * IC + ic) * 25 + t] * ssy);
        ((unsigned short*)(ws + WS_LWT ))[idx] = bf16r(lw [(oc * IC + ic) * 25 + t] * sl);
    }
    if (idx < 256) ws[WS_GAP + idx] = 0.f;
    if (fast && idx < 16) ws[WS_ZPAD + idx] = 0.f;
    if (split) {
        // zero Y halo: 2064 halo px/batch x 8 batches x 8 chunks = 132096
        #pragma unroll
        for (int rep = 0; rep < 2; rep++) {
            int id = idx + rep * 102400;
            if (id < 132096) {
                int bb = id / 16512, rm = id % 16512;
                int hp = rm >> 3, ch = rm & 7;
                int row, col;
                if (hp < 1040) { int rr = hp / 260; row = (rr < 2) ? rr : 256 + rr; col = hp % 260; }
                else { int j2 = hp - 1040; row = 2 + (j2 >> 2); int cv = j2 & 3; col = (cv < 2) ? cv : 256 + cv; }
                *(uint4*)((short*)(ws + WS_Y) + (((size_t)bb * YP + row * YW + col) * 64 + ch * 8)) = make_uint4(0u, 0u, 0u, 0u);
            }
        }
    }
    if (idx < 64) {
        float s1 = mbn1[idx] * rsqrtf(mbn1[192 + idx] + EPS);
        ws[WS_B1F + idx] = (mb1[idx] - mbn1[128 + idx]) * s1 + mbn1[64 + idx];
        float s2 = mbn2[idx] * rsqrtf(mbn2[192 + idx] + EPS);
        ws[WS_B2F + idx] = (mb2[idx] - mbn2[128 + idx]) * s2 + mbn2[64 + idx];
        float sx = sxbn[idx] * rsqrtf(sxbn[192 + idx] + EPS);
        ws[WS_SXBF + idx] = (sxb[idx] - sxbn[128 + idx]) * sx + sxbn[64 + idx];
        float sy = sybn[idx] * rsqrtf(sybn[192 + idx] + EPS);
        ws[WS_SYBF + idx] = (syb[idx] - sybn[128 + idx]) * sy + sybn[64 + idx];
        float sl = lbn[idx] * rsqrtf(lbn[192 + idx] + EPS);
        ws[WS_LBF + idx] = (lb[idx] - lbn[128 + idx]) * sl + lbn[64 + idx];
    }
}

// ------------------------------------------------------------------
// FAST path: NCHW fp32 -> padded NHWC bf16 xt (+ halo zeroing) + GAP.
// ------------------------------------------------------------------
__global__ void __launch_bounds__(256, 2)
xform_kernel(const float* __restrict__ x, float* __restrict__ ws) {
    int b = blockIdx.y, row = blockIdx.x, t = threadIdx.x;
    const float* xb = x + (size_t)b * (IC * HH * WW) + (size_t)row * WW;
    short* xtB = (short*)(ws + WS_XT) + (size_t)b * XTP * 32;

    unsigned int pk[16];
    #pragma unroll
    for (int k = 0; k < 32; k += 2) {
        float v0 = xb[(size_t)k * (HH * WW) + t];
        float v1 = xb[(size_t)(k + 1) * (HH * WW) + t];
        pk[k >> 1] = (unsigned int)bf16r(v0) | ((unsigned int)bf16r(v1) << 16);
    }
    uint4* dp = (uint4*)(xtB + ((size_t)(row + 3) * XTW + (t + 3)) * 32);
    dp[0] = make_uint4(pk[0],  pk[1],  pk[2],  pk[3]);
    dp[1] = make_uint4(pk[4],  pk[5],  pk[6],  pk[7]);
    dp[2] = make_uint4(pk[8],  pk[9],  pk[10], pk[11]);
    dp[3] = make_uint4(pk[12], pk[13], pk[14], pk[15]);

    if (t < 32) {
        int px = t >> 2, q = t & 3;
        int col = (px < 3) ? px : 256 + px;
        ((uint4*)(xtB + ((size_t)(row + 3) * XTW + col) * 32))[q] = make_uint4(0u, 0u, 0u, 0u);
    }
    if (row == 0) {
        for (int i = t; i < 3 * XTW * 4; i += 256) {
            int px = i >> 2, q = i & 3;
            ((uint4*)(xtB + ((size_t)(px / XTW) * XTW + (px % XTW)) * 32))[q] = make_uint4(0u, 0u, 0u, 0u);
        }
    }
    if (row == HH - 1) {
        for (int i = t; i < 5 * XTW * 4; i += 256) {
            int px = i >> 2, q = i & 3;
            ((uint4*)(xtB + ((size_t)(259 + px / XTW) * XTW + (px % XTW)) * 32))[q] = make_uint4(0u, 0u, 0u, 0u);
        }
    }

    __shared__ float gl[32];
    int w = t >> 6, lane = t & 63;
    #pragma unroll
    for (int kk = 0; kk < 8; kk++) {
        int k = w * 8 + kk;
        const float* rp = xb + (size_t)k * (HH * WW);
        float s = rp[lane] + rp[lane + 64] + rp[lane + 128] + rp[lane + 192];
        #pragma unroll
        for (int off = 32; off; off >>= 1) s += __shfl_down(s, off, 64);
        if (lane == 0) gl[k] = s;
    }
    __syncthreads();
    if (t < 32) atomicAdd(ws + WS_GAP + b * 32 + t, gl[t] * (1.f / (HH * WW)));
}

__global__ void gap_kernel(const float* __restrict__ x, float* __restrict__ ws) {
    int bc = blockIdx.x;
    const float4* p = (const float4*)(x + (size_t)bc * (HH * WW));
    float s = 0.f;
    for (int i = threadIdx.x; i < (HH * WW) / 4; i += 256) {
        float4 v = p[i];
        s += (v.x + v.y) + (v.z + v.w);
    }
    #pragma unroll
    for (int off = 32; off; off >>= 1) s += __shfl_down(s, off, 64);
    __shared__ float red[4];
    int lane = threadIdx.x & 63, w = threadIdx.x >> 6;
    if (lane == 0) red[w] = s;
    __syncthreads();
    if (threadIdx.x == 0)
        ws[WS_GAP + bc] = (red[0] + red[1] + red[2] + red[3]) * (1.f / (HH * WW));
}

__global__ void gate_kernel(const float* __restrict__ w1, const float* __restrict__ b1,
                            const float* __restrict__ gbn,
                            const float* __restrict__ w2, const float* __restrict__ b2,
                            float* __restrict__ ws) {
    __shared__ float hsh[8][32];
    int tid = threadIdx.x;
    int b = tid >> 5, j = tid & 31;
    float acc = b1[j];
    for (int i = 0; i < 32; i++) acc += ws[WS_GAP + b * 32 + i] * w1[j * 32 + i];
    float s = gbn[j] * rsqrtf(gbn[96 + j] + EPS);
    hsh[b][j] = tanhf((acc - gbn[64 + j]) * s + gbn[32 + j]);
    __syncthreads();
    if (tid < 8) {
        float best = -1e30f; int bi = 0;
        for (int c = 0; c < 3; c++) {
            float k = b2[c];
            for (int jj = 0; jj < 32; jj++) k += hsh[tid][jj] * w2[c * 32 + jj];
            if (k > best) { best = k; bi = c; }
        }
        ((int*)ws)[WS_BIDX + tid] = bi;
    }
}

// ------------------------------------------------------------------
// SPLIT pass 1: conv1 3x3+bn+relu -> padded Y (bf16 NHWC). (R11-verified.)
// ------------------------------------------------------------------
__global__ void __launch_bounds__(256, 2)
conv1_kernel(float* __restrict__ ws) {
    __shared__ __align__(1024) short xs[10752];   // 21504 B (324 px * 64B + pad)

    int b = blockIdx.y;
    if (((const int*)ws)[WS_BIDX + b] != 0) return;
    int tile = blockIdx.x;
    int ty = (tile >> 4) * 16, tx = (tile & 15) * 16;
    int tid = threadIdx.x;
    int w = tid >> 6, lane = tid & 63, n = lane & 15, quad = lane >> 4;

    const short* xtb = (const short*)(ws + WS_XT) + (size_t)b * (XTP * 32);
    for (int c = w; c < 21; c += 4) {
        int D = c * 1024 + (lane << 4);
        int L = D ^ (((D >> 7) & 7) << 4);
        int pL = L >> 6, qL = (L >> 4) & 3;
        int rr = pL / 18, cc2 = pL - rr * 18;
        if (pL >= 324) { rr = 0; cc2 = 0; }   // tail chunks: harmless refetch
        const void* src = (const void*)(xtb + ((size_t)((ty + 2 + rr) * XTW + tx + 2 + cc2)) * 32 + (qL << 3));
        gld16(src, (const void*)((const char*)xs + c * 1024));
    }

    auto ldb = [&](int r, int c) -> bf16x8 {
        int L = ((r * 18 + c) << 6) + (quad << 4);
        int A = L ^ (((L >> 7) & 7) << 4);
        return *(const bf16x8*)((const char*)xs + A);
    };

    const short* w1v = (const short*)(ws + WS_W1F);
    short* Yb = (short*)(ws + WS_Y) + (size_t)b * ((size_t)YP * 64);

    f32x4 a1[4][4];
    #pragma unroll
    for (int i = 0; i < 4; i++)
        #pragma unroll
        for (int jj = 0; jj < 4; jj++) a1[i][jj] = (f32x4){0.f, 0.f, 0.f, 0.f};

    int R0 = w * 4;

    __syncthreads();  // xs staged (drains vmcnt)

    #pragma unroll
    for (int dw = 0; dw < 3; dw++) {
        bf16x8 w1f[3][4];
        #pragma unroll
        for (int dh = 0; dh < 3; dh++) {
            int t = dh * 3 + dw;
            #pragma unroll
            for (int o4 = 0; o4 < 4; o4++)
                w1f[dh][o4] = *(const bf16x8*)(w1v + (((((o4 >> 1) * 9 + t) * 2) + (o4 & 1)) * 64 + lane) * 8);
        }
        bf16x8 bfr[6];
        #pragma unroll
        for (int rI = 0; rI < 6; rI++)
            bfr[rI] = ldb(R0 + rI, n + dw);
        #pragma unroll
        for (int dh = 0; dh < 3; dh++)
            #pragma unroll
            for (int r4 = 0; r4 < 4; r4++) {
                #pragma unroll
                for (int o4 = 0; o4 < 4; o4++)
                    a1[r4][o4] = __builtin_amdgcn_mfma_f32_16x16x32_bf16(w1f[dh][o4], bfr[r4 + dh], a1[r4][o4], 0, 0, 0);
            }
    }

    #pragma unroll
    for (int o4 = 0; o4 < 4; o4++) {
        float bias1[4];
        #pragma unroll
        for (int r = 0; r < 4; r++)
            bias1[r] = ws[WS_B1F + o4 * 16 + quad * 4 + r];
        #pragma unroll
        for (int r4 = 0; r4 < 4; r4++) {
            float v0 = fmaxf(a1[r4][o4][0] + bias1[0], 0.f);
            float v1 = fmaxf(a1[r4][o4][1] + bias1[1], 0.f);
            float v2 = fmaxf(a1[r4][o4][2] + bias1[2], 0.f);
            float v3 = fmaxf(a1[r4][o4][3] + bias1[3], 0.f);
            uint2 pkk;
            pkk.x = (unsigned int)bf16r(v0) | ((unsigned int)bf16r(v1) << 16);
            pkk.y = (unsigned int)bf16r(v2) | ((unsigned int)bf16r(v3) << 16);
            int row = ty + R0 + r4 + 2, col = tx + n + 2;
            *(uint2*)(Yb + ((size_t)(row * YW + col)) * 64 + o4 * 16 + quad * 4) = pkk;
        }
    }
}

// ------------------------------------------------------------------
// SPLIT pass 2: conv2 5x5+bn+relu from padded Y. R11-verified structure
// (256 thr, (256,2), afq[4][4] ring, acc2[4][4], 0 bank conflicts).
// R15: + s_setprio(1) around the per-k-step MFMA cluster (T5): conv2's
// k-loop is barrier-free so resident waves sit at different phases
// (ds_read vs MFMA-ready) — the regime where setprio measured +4-7%.
// Zero structural risk (2 SALU ops; cannot spill or change results).
// ------------------------------------------------------------------
__global__ void __launch_bounds__(256, 2)
conv2_kernel(const float* __restrict__ ws, float* __restrict__ out) {
    __shared__ __align__(1024) short ysl[25600];   // 51200 B (400 px * 128B)

    int b = blockIdx.y;
    if (((const int*)ws)[WS_BIDX + b] != 0) return;
    int tile = blockIdx.x;
    int ty = (tile >> 4) * 16, tx = (tile & 15) * 16;
    int tid = threadIdx.x;
    int w = tid >> 6, lane = tid & 63, n = lane & 15, quad = lane >> 4;

    const short* Yb = (const short*)(ws + WS_Y) + (size_t)b * ((size_t)YP * 64);
    for (int c = w; c < 50; c += 4) {
        int D = c * 1024 + (lane << 4);
        int L = D ^ (((D >> 7) & 7) << 4);
        int pL = L >> 7, sub = (L >> 4) & 7;
        int rr = pL / 20, cc2 = pL - rr * 20;
        const void* src = (const void*)(Yb + ((size_t)((ty + rr) * YW + tx + cc2)) * 64 + (sub << 3));
        gld16(src, (const void*)((const char*)ysl + c * 1024));
    }

    auto ldy = [&](int px, int h) -> bf16x8 {
        int L = (px << 7) + (h << 6) + (quad << 4);
        int A = L ^ (((L >> 7) & 7) << 4);
        return *(const bf16x8*)((const char*)ysl + A);
    };

    const bf16x8* w2v = (const bf16x8*)(ws + WS_W2F);

    f32x4 acc2[4][4];
    #pragma unroll
    for (int i = 0; i < 4; i++)
        #pragma unroll
        for (int jj = 0; jj < 4; jj++) acc2[i][jj] = (f32x4){0.f, 0.f, 0.f, 0.f};
    int mrow0 = w * 4;

    __syncthreads();  // ysl staged (drains vmcnt) — the ONLY barrier

    #pragma unroll 1
    for (int h = 0; h < 2; h++) {
        const bf16x8* w2h = w2v + (size_t)h * 100 * 64;
        bf16x8 afq[4][4];
        #pragma unroll
        for (int kp = 0; kp < 4; kp++) {
            int tn = (kp % 5) * 5 + (kp / 5);
            int base = tn * 256 + lane;
            afq[kp][0] = w2h[base];       afq[kp][1] = w2h[base + 64];
            afq[kp][2] = w2h[base + 128]; afq[kp][3] = w2h[base + 192];
        }
        bf16x8 bfr2[8];
        #pragma unroll
        for (int k = 0; k < 25; k++) {
            int dw = k / 5, dh = k % 5;
            if (dh == 0) {
                #pragma unroll
                for (int rI = 0; rI < 8; rI++)
                    bfr2[rI] = ldy((mrow0 + rI) * 20 + n + dw, h);
            }
            __builtin_amdgcn_s_setprio(1);
            #pragma unroll
            for (int r4 = 0; r4 < 4; r4++) {
                bf16x8 bb = bfr2[r4 + dh];
                acc2[r4][0] = __builtin_amdgcn_mfma_f32_16x16x32_bf16(afq[k & 3][0], bb, acc2[r4][0], 0, 0, 0);
                acc2[r4][1] = __builtin_amdgcn_mfma_f32_16x16x32_bf16(afq[k & 3][1], bb, acc2[r4][1], 0, 0, 0);
                acc2[r4][2] = __builtin_amdgcn_mfma_f32_16x16x32_bf16(afq[k & 3][2], bb, acc2[r4][2], 0, 0, 0);
                acc2[r4][3] = __builtin_amdgcn_mfma_f32_16x16x32_bf16(afq[k & 3][3], bb, acc2[r4][3], 0, 0, 0);
            }
            __builtin_amdgcn_s_setprio(0);
            if (k + 4 < 25) {
                int kk = k + 4;
                int tn = (kk % 5) * 5 + (kk / 5);
                int base = tn * 256 + lane;
                afq[k & 3][0] = w2h[base];       afq[k & 3][1] = w2h[base + 64];
                afq[k & 3][2] = w2h[base + 128]; afq[k & 3][3] = w2h[base + 192];
            }
        }
    }

    float bias2[4][4];
    #pragma unroll
    for (int oct = 0; oct < 4; oct++)
        #pragma unroll
        for (int r = 0; r < 4; r++)
            bias2[oct][r] = ws[WS_B2F + oct * 16 + quad * 4 + r];

    float* ob = out + (size_t)b * OC * HH * WW;
    #pragma unroll
    for (int r4 = 0; r4 < 4; r4++) {
        int orow = mrow0 + r4;
        #pragma unroll
        for (int oct = 0; oct < 4; oct++) {
            #pragma unroll
            for (int r = 0; r < 4; r++) {
                int oc = oct * 16 + quad * 4 + r;
                float v = fmaxf(acc2[r4][oct][r] + bias2[oct][r], 0.f);
                ob[(size_t)oc * (HH * WW) + (ty + orow) * WW + tx + n] = v;
            }
        }
    }
}

// ------------------------------------------------------------------
// FUSED main (tier-2/3 fallback; R6-verified body).
// ------------------------------------------------------------------
template <int ASYNC>
__global__ void __launch_bounds__(256, 2)
main_kernel(const float* __restrict__ x, const float* __restrict__ ws, float* __restrict__ out) {
    __shared__ __align__(1024) short xs[ASYNC ? 496 * 32 : 484 * XSTR];
    __shared__ __align__(16)   short ys[400 * YSTR];

    int b = blockIdx.y;
    if (((const int*)ws)[WS_BIDX + b] != 0) return;
    int tile = blockIdx.x;
    int ty = (tile >> 4) * 16, tx = (tile & 15) * 16;
    int tid = threadIdx.x;
    int w = tid >> 6, lane = tid & 63, n = lane & 15, quad = lane >> 4;

    if constexpr (ASYNC) {
        const short* xtb = (const short*)(ws + WS_XT) + (size_t)b * (XTP * 32);
        for (int c = w; c < 31; c += 4) {
            int D = c * 1024 + (lane << 4);
            int L = D ^ (((D >> 7) & 7) << 4);
            int pL = L >> 6, qL = (L >> 4) & 3;
            int rr = pL / 22, cc2 = pL - rr * 22;
            if (pL >= 484) { rr = 21; cc2 = 21; }
            const void* src = (const void*)(xtb + ((size_t)((ty + rr) * XTW + tx + cc2)) * 32 + (qL << 3));
            gld16(src, (const void*)((const char*)xs + c * 1024));
        }
    } else {
        const float* xb = x + (size_t)b * IC * HH * WW;
        for (int p = tid; p < 484; p += 256) {
            int rr = p / 22, cc = p % 22;
            int gy = ty - 3 + rr, gx = tx - 3 + cc;
            bool v = ((unsigned)gy < HH) && ((unsigned)gx < WW);
            const float* xp = xb + gy * WW + gx;
            short* dst = xs + p * XSTR;
            #pragma unroll
            for (int ic = 0; ic < IC; ic += 4) {
                float f0 = v ? xp[(size_t)(ic + 0) * (HH * WW)] : 0.f;
                float f1 = v ? xp[(size_t)(ic + 1) * (HH * WW)] : 0.f;
                float f2 = v ? xp[(size_t)(ic + 2) * (HH * WW)] : 0.f;
                float f3 = v ? xp[(size_t)(ic + 3) * (HH * WW)] : 0.f;
                uint2 pk;
                pk.x = (unsigned int)bf16r(f0) | ((unsigned int)bf16r(f1) << 16);
                pk.y = (unsigned int)bf16r(f2) | ((unsigned int)bf16r(f3) << 16);
                *(uint2*)(dst + ic) = pk;
            }
        }
    }

    auto ldb = [&](int P) -> bf16x8 {
        if constexpr (ASYNC) {
            int L = (P << 6) + (quad << 4);
            int A = L ^ (((L >> 7) & 7) << 4);
            return *(const bf16x8*)((const char*)xs + A);
        } else {
            return *(const bf16x8*)(xs + P * XSTR + quad * 8);
        }
    };

    const short* w1v = (const short*)(ws + WS_W1F);
    const bf16x8* w2v = (const bf16x8*)(ws + WS_W2F);

    f32x4 acc2[4][4];
    #pragma unroll
    for (int i = 0; i < 4; i++)
        #pragma unroll
        for (int jj = 0; jj < 4; jj++) acc2[i][jj] = (f32x4){0.f, 0.f, 0.f, 0.f};
    int mrow0 = w * 4;
    int yr0   = w * 5;

    __syncthreads();

    #pragma unroll 1
    for (int h = 0; h < 2; h++) {
        if (h) __syncthreads();

        #pragma unroll
        for (int cg = 0; cg < 2; cg++) {
            int cb = cg * 4;
            f32x4 a1[5][2];
            #pragma unroll
            for (int rr = 0; rr < 5; rr++) {
                a1[rr][0] = (f32x4){0.f, 0.f, 0.f, 0.f};
                a1[rr][1] = (f32x4){0.f, 0.f, 0.f, 0.f};
            }
            #pragma unroll
            for (int dw = 0; dw < 3; dw++) {
                bf16x8 w1f[3][2];
                #pragma unroll
                for (int dh = 0; dh < 3; dh++) {
                    int t = dh * 3 + dw;
                    w1f[dh][0] = *(const bf16x8*)(w1v + (((h * 9 + t) * 2 + 0) * 64 + lane) * 8);
                    w1f[dh][1] = *(const bf16x8*)(w1v + (((h * 9 + t) * 2 + 1) * 64 + lane) * 8);
                }
                bf16x8 bfr[7];
                #pragma unroll
                for (int rI = 0; rI < 7; rI++)
                    bfr[rI] = ldb((yr0 + rI) * 22 + cb + n + dw);
                #pragma unroll
                for (int dh = 0; dh < 3; dh++)
                    #pragma unroll
                    for (int rr = 0; rr < 5; rr++) {
                        a1[rr][0] = __builtin_amdgcn_mfma_f32_16x16x32_bf16(w1f[dh][0], bfr[rr + dh], a1[rr][0], 0, 0, 0);
                        a1[rr][1] = __builtin_amdgcn_mfma_f32_16x16x32_bf16(w1f[dh][1], bfr[rr + dh], a1[rr][1], 0, 0, 0);
                    }
            }
            #pragma unroll
            for (int oct = 0; oct < 2; oct++) {
                float bias1[4];
                #pragma unroll
                for (int r = 0; r < 4; r++)
                    bias1[r] = ws[WS_B1F + h * 32 + oct * 16 + quad * 4 + r];
                #pragma unroll
                for (int rr = 0; rr < 5; rr++) {
                    int yr = yr0 + rr;
                    int gy2 = ty - 2 + yr, gx2 = tx - 2 + cb + n;
                    bool inb = ((unsigned)gy2 < HH) && ((unsigned)gx2 < WW);
                    float v0 = inb ? fmaxf(a1[rr][oct][0] + bias1[0], 0.f) : 0.f;
                    float v1 = inb ? fmaxf(a1[rr][oct][1] + bias1[1], 0.f) : 0.f;
                    float v2 = inb ? fmaxf(a1[rr][oct][2] + bias1[2], 0.f) : 0.f;
                    float v3 = inb ? fmaxf(a1[rr][oct][3] + bias1[3], 0.f) : 0.f;
                    uint2 pkk;
                    pkk.x = (unsigned int)bf16r(v0) | ((unsigned int)bf16r(v1) << 16);
                    pkk.y = (unsigned int)bf16r(v2) | ((unsigned int)bf16r(v3) << 16);
                    *(uint2*)(ys + (yr * 20 + cb + n) * YSTR + oct * 16 + quad * 4) = pkk;
                }
            }
        }
        __syncthreads();

        const bf16x8* w2h = w2v + (size_t)h * 100 * 64;
        bf16x8 afq[4][4];
        #pragma unroll
        for (int kp = 0; kp < 4; kp++) {
            int tn = (kp % 5) * 5 + (kp / 5);
            int base = tn * 256 + lane;
            afq[kp][0] = w2h[base];       afq[kp][1] = w2h[base + 64];
            afq[kp][2] = w2h[base + 128]; afq[kp][3] = w2h[base + 192];
        }
        bf16x8 bfr2[8];
        #pragma unroll
        for (int k = 0; k < 25; k++) {
            int dw = k / 5, dh = k % 5;
            if (dh == 0) {
                #pragma unroll
                for (int rI = 0; rI < 8; rI++)
                    bfr2[rI] = *(const bf16x8*)(ys + ((mrow0 + rI) * 20 + n + dw) * YSTR + quad * 8);
            }
            #pragma unroll
            for (int r4 = 0; r4 < 4; r4++) {
                bf16x8 bb = bfr2[r4 + dh];
                acc2[r4][0] = __builtin_amdgcn_mfma_f32_16x16x32_bf16(afq[k & 3][0], bb, acc2[r4][0], 0, 0, 0);
                acc2[r4][1] = __builtin_amdgcn_mfma_f32_16x16x32_bf16(afq[k & 3][1], bb, acc2[r4][1], 0, 0, 0);
                acc2[r4][2] = __builtin_amdgcn_mfma_f32_16x16x32_bf16(afq[k & 3][2], bb, acc2[r4][2], 0, 0, 0);
                acc2[r4][3] = __builtin_amdgcn_mfma_f32_16x16x32_bf16(afq[k & 3][3], bb, acc2[r4][3], 0, 0, 0);
            }
            if (k + 4 < 25) {
                int kk = k + 4;
                int tn = (kk % 5) * 5 + (kk / 5);
                int base = tn * 256 + lane;
                afq[k & 3][0] = w2h[base];       afq[k & 3][1] = w2h[base + 64];
                afq[k & 3][2] = w2h[base + 128]; afq[k & 3][3] = w2h[base + 192];
            }
        }
    }

    float bias2[4][4];
    #pragma unroll
    for (int oct = 0; oct < 4; oct++)
        #pragma unroll
        for (int r = 0; r < 4; r++)
            bias2[oct][r] = ws[WS_B2F + oct * 16 + quad * 4 + r];

    float* ob = out + (size_t)b * OC * HH * WW;
    #pragma unroll
    for (int r4 = 0; r4 < 4; r4++) {
        int orow = mrow0 + r4;
        #pragma unroll
        for (int oct = 0; oct < 4; oct++) {
            #pragma unroll
            for (int r = 0; r < 4; r++) {
                int oc = oct * 16 + quad * 4 + r;
                float v = fmaxf(acc2[r4][oct][r] + bias2[oct][r], 0.f);
                ob[(size_t)oc * (HH * WW) + (ty + orow) * WW + tx + n] = v;
            }
        }
    }
}

// ------------------------------------------------------------------
// edge branches via MFMA (R8-verified padded-xt staging; early-exit).
// ------------------------------------------------------------------
template <int ASYNC>
__global__ void __launch_bounds__(256, 2)
edge_kernel(const float* __restrict__ x, const float* __restrict__ ws, float* __restrict__ out) {
    constexpr float KSX[9] = {1, 0, -1, 2, 0, -2, 1, 0, -1};
    constexpr float KSY[9] = {1, 2, 1, 0, 0, 0, -1, -2, -1};
    constexpr float KLP[9] = {0, 1, 0, 1, -4, 1, 0, 1, 0};

    __shared__ __align__(1024) short xs[ASYNC ? 496 * 32 : 484 * XSTR];
    __shared__ __align__(16)   short ys[400 * YSTR];

    int b = blockIdx.y;
    int sel = ((const int*)ws)[WS_BIDX + b];
    if (sel == 0) return;
    int tile = blockIdx.x;
    int ty = (tile >> 4) * 16, tx = (tile & 15) * 16;
    int tid = threadIdx.x;
    int w = tid >> 6, lane = tid & 63, n = lane & 15, quad = lane >> 4;

    if constexpr (ASYNC) {
        const short* xtb = (const short*)(ws + WS_XT) + (size_t)b * (XTP * 32);
        const void* zp = (const void*)(ws + WS_ZPAD);
        for (int c = w; c < 31; c += 4) {
            int D = c * 1024 + (lane << 4);
            int L = D ^ (((D >> 7) & 7) << 4);
            int pL = L >> 6, qL = (L >> 4) & 3;
            int rr = pL / 22, cc2 = pL - rr * 22;
            bool v = (pL < 484);
            const void* src = v ? (const void*)(xtb + ((size_t)((ty + rr) * XTW + tx + cc2)) * 32 + (qL << 3)) : zp;
            gld16(src, (const void*)((const char*)xs + c * 1024));
        }
    } else {
        const float* xb = x + (size_t)b * IC * HH * WW;
        for (int p = tid; p < 484; p += 256) {
            int rr = p / 22, cc = p % 22;
            int gy = ty - 3 + rr, gx = tx - 3 + cc;
            bool v = ((unsigned)gy < HH) && ((unsigned)gx < WW);
            const float* xp = xb + gy * WW + gx;
            short* dst = xs + p * XSTR;
            #pragma unroll
            for (int ic = 0; ic < IC; ic += 4) {
                float f0 = v ? xp[(size_t)(ic + 0) * (HH * WW)] : 0.f;
                float f1 = v ? xp[(size_t)(ic + 1) * (HH * WW)] : 0.f;
                float f2 = v ? xp[(size_t)(ic + 2) * (HH * WW)] : 0.f;
                float f3 = v ? xp[(size_t)(ic + 3) * (HH * WW)] : 0.f;
                uint2 pk;
                pk.x = (unsigned int)bf16r(f0) | ((unsigned int)bf16r(f1) << 16);
                pk.y = (unsigned int)bf16r(f2) | ((unsigned int)bf16r(f3) << 16);
                *(uint2*)(dst + ic) = pk;
            }
        }
    }

    auto ldq = [&](int P, int q) -> bf16x8 {
        if constexpr (ASYNC) {
            int L = (P << 6) + (q << 4);
            int A = L ^ (((L >> 7) & 7) << 4);
            return *(const bf16x8*)((const char*)xs + A);
        } else {
            return *(const bf16x8*)(xs + P * XSTR + q * 8);
        }
    };

    int mrow0 = w * 4;
    int npass = (sel == 1) ? 2 : 1;
    f32x4 accA[4][4];
    f32x4 acc2[4][4];

    __syncthreads();

    #pragma unroll 1
    for (int pass = 0; pass < npass; pass++) {
        int kid = (sel == 1) ? pass : 2;
        if (pass) __syncthreads();

        for (int t2 = tid; t2 < 1600; t2 += 256) {
            int q = t2 & 3, px = t2 >> 2;
            int pr = px / 20, pc = px - pr * 20;
            bool inb = ((unsigned)(ty - 2 + pr) < HH) && ((unsigned)(tx - 2 + pc) < WW);
            float a[8] = {0.f, 0.f, 0.f, 0.f, 0.f, 0.f, 0.f, 0.f};
            if (inb) {
                #pragma unroll
                for (int dr = 0; dr < 3; dr++)
                    #pragma unroll
                    for (int dc = 0; dc < 3; dc++) {
                        float kv = (kid == 0) ? KSX[dr * 3 + dc]
                                 : (kid == 1) ? KSY[dr * 3 + dc]
                                              : KLP[dr * 3 + dc];
                        if (kv != 0.f) {
                            bf16x8 v = ldq((pr + dr) * 22 + pc + dc, q);
                            #pragma unroll
                            for (int j = 0; j < 8; j++)
                                a[j] += kv * bf2f((unsigned short)v[j]);
                        }
                    }
            }
            uint4 pk;
            pk.x = (unsigned int)bf16r(a[0]) | ((unsigned int)bf16r(a[1]) << 16);
            pk.y = (unsigned int)bf16r(a[2]) | ((unsigned int)bf16r(a[3]) << 16);
            pk.z = (unsigned int)bf16r(a[4]) | ((unsigned int)bf16r(a[5]) << 16);
            pk.w = (unsigned int)bf16r(a[6]) | ((unsigned int)bf16r(a[7]) << 16);
            *(uint4*)(ys + px * YSTR + q * 8) = pk;
        }
        __syncthreads();

        #pragma unroll
        for (int i = 0; i < 4; i++)
            #pragma unroll
            for (int jj = 0; jj < 4; jj++) acc2[i][jj] = (f32x4){0.f, 0.f, 0.f, 0.f};

        const bf16x8* wf = (const bf16x8*)(ws + (kid == 0 ? WS_SXWT : kid == 1 ? WS_SYWT : WS_LWT));
        bf16x8 afq[2][4];
        #pragma unroll
        for (int kp = 0; kp < 2; kp++) {
            int tn = kp * 5;
            int base = tn * 256 + lane;
            afq[kp][0] = wf[base];       afq[kp][1] = wf[base + 64];
            afq[kp][2] = wf[base + 128]; afq[kp][3] = wf[base + 192];
        }
        bf16x8 bfr2[8];
        #pragma unroll
        for (int k = 0; k < 25; k++) {
            int dw = k / 5, dh = k % 5;
            if (dh == 0) {
                #pragma unroll
                for (int rI = 0; rI < 8; rI++)
                    bfr2[rI] = *(const bf16x8*)(ys + ((mrow0 + rI) * 20 + n + dw) * YSTR + quad * 8);
            }
            #pragma unroll
            for (int r4 = 0; r4 < 4; r4++) {
                bf16x8 bb = bfr2[r4 + dh];
                acc2[r4][0] = __builtin_amdgcn_mfma_f32_16x16x32_bf16(afq[k & 1][0], bb, acc2[r4][0], 0, 0, 0);
                acc2[r4][1] = __builtin_amdgcn_mfma_f32_16x16x32_bf16(afq[k & 1][1], bb, acc2[r4][1], 0, 0, 0);
                acc2[r4][2] = __builtin_amdgcn_mfma_f32_16x16x32_bf16(afq[k & 1][2], bb, acc2[r4][2], 0, 0, 0);
                acc2[r4][3] = __builtin_amdgcn_mfma_f32_16x16x32_bf16(afq[k & 1][3], bb, acc2[r4][3], 0, 0, 0);
            }
            if (k + 2 < 25) {
                int kk = k + 2;
                int tn = (kk % 5) * 5 + (kk / 5);
                int base = tn * 256 + lane;
                afq[k & 1][0] = wf[base];       afq[k & 1][1] = wf[base + 64];
                afq[k & 1][2] = wf[base + 128]; afq[k & 1][3] = wf[base + 192];
            }
        }
        if (sel == 1 && pass == 0) {
            #pragma unroll
            for (int i = 0; i < 4; i++)
                #pragma unroll
                for (int jj = 0; jj < 4; jj++) accA[i][jj] = acc2[i][jj];
        }
    }

    float* ob = out + (size_t)b * OC * HH * WW;
    #pragma unroll
    for (int r4 = 0; r4 < 4; r4++) {
        int orow = mrow0 + r4;
        #pragma unroll
        for (int oct = 0; oct < 4; oct++) {
            #pragma unroll
            for (int r = 0; r < 4; r++) {
                int oc = oct * 16 + quad * 4 + r;
                float v;
                if (sel == 1) {
                    float vx = fmaxf(accA[r4][oct][r] + ws[WS_SXBF + oc], 0.f);
                    float vy = fmaxf(acc2[r4][oct][r] + ws[WS_SYBF + oc], 0.f);
                    v = 0.5f * (vx + vy);
                } else {
                    v = fmaxf(acc2[r4][oct][r] + ws[WS_LBF + oc], 0.f);
                }
                ob[(size_t)oc * (HH * WW) + (ty + orow) * WW + tx + n] = v;
            }
        }
    }
}

// ------------------------------------------------------------------
extern "C" void kernel_launch(void* const* d_in, const int* in_sizes, int n_in,
                              void* d_out, int out_size, void* d_ws, size_t ws_size,
                              hipStream_t stream) {
    const float* x    = (const float*)d_in[0];
    const float* gw1  = (const float*)d_in[1];
    const float* gb1  = (const float*)d_in[2];
    const float* gbn  = (const float*)d_in[3];
    const float* gw2  = (const float*)d_in[4];
    const float* gb2  = (const float*)d_in[5];
    const float* mw1  = (const float*)d_in[6];
    const float* mb1  = (const float*)d_in[7];
    const float* mbn1 = (const float*)d_in[8];
    const float* mw2  = (const float*)d_in[9];
    const float* mb2  = (const float*)d_in[10];
    const float* mbn2 = (const float*)d_in[11];
    const float* sxw  = (const float*)d_in[12];
    const float* sxb  = (const float*)d_in[13];
    const float* sxbn = (const float*)d_in[14];
    const float* syw  = (const float*)d_in[15];
    const float* syb  = (const float*)d_in[16];
    const float* sybn = (const float*)d_in[17];
    const float* lw   = (const float*)d_in[18];
    const float* lb   = (const float*)d_in[19];
    const float* lbn  = (const float*)d_in[20];
    float* ws  = (float*)d_ws;
    float* out = (float*)d_out;

    int fast  = (ws_size >= WS_NEED_FAST) ? 1 : 0;    // ~36.6 MB
    int split = (ws_size >= WS_NEED_SPLIT) ? 1 : 0;   // ~105 MB (verified engaged in R11)

    prep_kernel<<<400, 256, 0, stream>>>(mw1, mb1, mbn1, mw2, mb2, mbn2,
                                         sxw, sxb, sxbn, syw, syb, sybn, lw, lb, lbn, ws, fast, split);
    if (fast) {
        xform_kernel<<<dim3(HH, BB), 256, 0, stream>>>(x, ws);
    } else {
        gap_kernel<<<256, 256, 0, stream>>>(x, ws);
    }
    gate_kernel<<<1, 256, 0, stream>>>(gw1, gb1, gbn, gw2, gb2, ws);

    dim3 grid(256, BB);
    if (split) {
        conv1_kernel<<<grid, 256, 0, stream>>>(ws);
        conv2_kernel<<<grid, 256, 0, stream>>>(ws, out);
    } else if (fast) {
        main_kernel<1><<<grid, 256, 0, stream>>>(x, ws, out);
    } else {
        main_kernel<0><<<grid, 256, 0, stream>>>(x, ws, out);
    }
    if (fast) {
        edge_kernel<1><<<grid, 256, 0, stream>>>(x, ws, out);
    } else {
        edge_kernel<0><<<grid, 256, 0, stream>>>(x, ws, out);
    }
}